// Round 1
// baseline (796.615 us; speedup 1.0000x reference)
//
#include <hip/hip_runtime.h>

#define N_NODES 50000
#define N_EDGES 600000
#define B_GRAPHS 64
#define DH 128
#define PFEAT 32
#define NCLS 2
#define POOL_CH 512

// ---------- degree count ----------
__global__ void k_deg(const int* __restrict__ dst, int* __restrict__ deg) {
    int e = blockIdx.x * blockDim.x + threadIdx.x;
    if (e < N_EDGES) atomicAdd(&deg[dst[e]], 1);
}

// ---------- norm = clamp(deg,1)^-0.5 ----------
__global__ void k_norm(const int* __restrict__ deg, float* __restrict__ norm) {
    int n = blockIdx.x * blockDim.x + threadIdx.x;
    if (n < N_NODES) {
        int d = deg[n];
        if (d < 1) d = 1;
        norm[n] = rsqrtf((float)d);
    }
}

// ---------- single-block exclusive scan -> row_ptr ----------
__global__ void k_scan(const int* __restrict__ deg, int* __restrict__ row_ptr) {
    __shared__ int smem[1024];
    __shared__ int carry;
    if (threadIdx.x == 0) carry = 0;
    __syncthreads();
    for (int base = 0; base < N_NODES; base += 1024) {
        int i = base + threadIdx.x;
        int v = (i < N_NODES) ? deg[i] : 0;
        smem[threadIdx.x] = v;
        __syncthreads();
        for (int off = 1; off < 1024; off <<= 1) {
            int t = (threadIdx.x >= off) ? smem[threadIdx.x - off] : 0;
            __syncthreads();
            smem[threadIdx.x] += t;
            __syncthreads();
        }
        if (i < N_NODES) row_ptr[i + 1] = smem[threadIdx.x] + carry;
        __syncthreads();
        if (threadIdx.x == 0) carry += smem[1023];
        __syncthreads();
    }
    if (threadIdx.x == 0) row_ptr[0] = 0;
}

// ---------- scatter edges into CSR buckets ----------
__global__ void k_scatter(const int* __restrict__ src, const int* __restrict__ dst,
                          const int* __restrict__ row_ptr, int* __restrict__ cnt,
                          int* __restrict__ col) {
    int e = blockIdx.x * blockDim.x + threadIdx.x;
    if (e < N_EDGES) {
        int d = dst[e];
        int pos = atomicAdd(&cnt[d], 1);
        col[row_ptr[d] + pos] = src[e];
    }
}

// ---------- SpMM hop: out[v] = norm[v] * sum_{u in Nin(v)} in[u]*norm[u] ----------
__global__ __launch_bounds__(256) void k_spmm(const float* __restrict__ fin,
                                              const float* __restrict__ norm,
                                              const int* __restrict__ row_ptr,
                                              const int* __restrict__ col,
                                              float* __restrict__ fout) {
    int wave = threadIdx.x >> 6;
    int lane = threadIdx.x & 63;
    int v = blockIdx.x * 4 + wave;
    if (v >= N_NODES) return;
    int beg = row_ptr[v], end = row_ptr[v + 1];
    float2 acc = {0.f, 0.f};
    for (int e = beg; e < end; ++e) {
        int u = col[e];
        float nu = norm[u];
        const float2* r = (const float2*)(fin + (size_t)u * 128);
        float2 val = r[lane];
        acc.x += val.x * nu;
        acc.y += val.y * nu;
    }
    float nv = norm[v];
    float2* o = (float2*)(fout + (size_t)v * 128);
    float2 res;
    res.x = acc.x * nv;
    res.y = acc.y * nv;
    o[lane] = res;
}

// ---------- fp32 tiled GEMM: out = relu?( [A0|A1|A2] @ W + bias ) ----------
// A0/A1/A2: [N,128] row-major, W: [384,128] row-major, out: [N,128]
__global__ __launch_bounds__(256) void k_gemm(const float* __restrict__ A0,
                                              const float* __restrict__ A1,
                                              const float* __restrict__ A2,
                                              const float* __restrict__ W,
                                              const float* __restrict__ bias,
                                              float* __restrict__ out, int relu) {
    __shared__ float As[16 * 128];
    __shared__ float Ws[16 * 128];
    int tid = threadIdx.x;
    int tx = tid & 15;   // col group 0..15
    int ty = tid >> 4;   // row group 0..15
    int n0 = blockIdx.x * 128;
    float acc[8][8] = {{0.f}};
    const float* Aseg[3] = {A0, A1, A2};
    for (int kb = 0; kb < 24; ++kb) {
        const float* A = Aseg[kb >> 3];
        int klocal = (kb & 7) * 16;
        // A tile: As[k*128+m] = A[(n0+m)*128 + klocal + k]
#pragma unroll
        for (int i = 0; i < 8; ++i) {
            int idx = tid + i * 256;
            int m = idx >> 4, k = idx & 15;
            int row = n0 + m;
            As[k * 128 + m] = (row < N_NODES) ? A[(size_t)row * 128 + klocal + k] : 0.f;
        }
        // W tile: Ws[k*128+j] = W[(kb*16+k)*128 + j]
#pragma unroll
        for (int i = 0; i < 8; ++i) {
            int idx = tid + i * 256;
            Ws[idx] = W[(size_t)kb * 16 * 128 + idx];
        }
        __syncthreads();
#pragma unroll
        for (int k = 0; k < 16; ++k) {
            float ra[8], rb[8];
#pragma unroll
            for (int i = 0; i < 8; ++i) ra[i] = As[k * 128 + ty * 8 + i];
#pragma unroll
            for (int j = 0; j < 8; ++j) rb[j] = Ws[k * 128 + tx * 8 + j];
#pragma unroll
            for (int i = 0; i < 8; ++i)
#pragma unroll
                for (int j = 0; j < 8; ++j) acc[i][j] += ra[i] * rb[j];
        }
        __syncthreads();
    }
#pragma unroll
    for (int i = 0; i < 8; ++i) {
        int row = n0 + ty * 8 + i;
        if (row < N_NODES) {
#pragma unroll
            for (int j = 0; j < 8; ++j) {
                float v = acc[i][j] + bias[tx * 8 + j];
                if (relu) v = fmaxf(v, 0.f);
                out[(size_t)row * 128 + tx * 8 + j] = v;
            }
        }
    }
}

// ---------- pooling: per-chunk accumulation exploiting sorted graph_ids ----------
__global__ void k_pool(const float* __restrict__ x, const int* __restrict__ gid,
                       float* __restrict__ gsum, int* __restrict__ gcnt) {
    int d = threadIdx.x;  // 0..127
    int n0 = blockIdx.x * POOL_CH;
    if (n0 >= N_NODES) return;
    int n1 = n0 + POOL_CH;
    if (n1 > N_NODES) n1 = N_NODES;
    float acc = 0.f;
    int cnt = 0;
    int gp = gid[n0];
    for (int nn = n0; nn < n1; ++nn) {
        int g = gid[nn];
        if (g != gp) {
            atomicAdd(&gsum[gp * 128 + d], acc);
            if (d == 0) atomicAdd(&gcnt[gp], cnt);
            acc = 0.f;
            cnt = 0;
            gp = g;
        }
        acc += x[(size_t)nn * 128 + d];
        cnt++;
    }
    atomicAdd(&gsum[gp * 128 + d], acc);
    if (d == 0) atomicAdd(&gcnt[gp], cnt);
}

// ---------- final: out[b,c] = mean(hg) @ Wc + perm @ Wc_tail + bc ----------
__global__ void k_final(const float* __restrict__ gsum, const int* __restrict__ gcnt,
                        const float* __restrict__ perm, const float* __restrict__ Wc,
                        const float* __restrict__ bc, float* __restrict__ out) {
    int t = threadIdx.x;
    if (t >= B_GRAPHS * NCLS) return;
    int b = t / NCLS, c = t % NCLS;
    float cf = (float)gcnt[b];
    if (cf < 1.f) cf = 1.f;
    float acc = bc[c];
    for (int d = 0; d < DH; ++d) acc += (gsum[b * 128 + d] / cf) * Wc[d * NCLS + c];
    for (int p = 0; p < PFEAT; ++p) acc += perm[b * PFEAT + p] * Wc[(DH + p) * NCLS + c];
    out[t] = acc;
}

extern "C" void kernel_launch(void* const* d_in, const int* in_sizes, int n_in,
                              void* d_out, int out_size, void* d_ws, size_t ws_size,
                              hipStream_t stream) {
    const float* h    = (const float*)d_in[0];
    const int*   src  = (const int*)d_in[1];
    const int*   dst  = (const int*)d_in[2];
    const int*   gid  = (const int*)d_in[3];
    const float* perm = (const float*)d_in[4];
    const float* W1   = (const float*)d_in[5];
    const float* b1   = (const float*)d_in[6];
    const float* W2   = (const float*)d_in[7];
    const float* b2   = (const float*)d_in[8];
    const float* Wc   = (const float*)d_in[9];
    const float* bc   = (const float*)d_in[10];
    float* out = (float*)d_out;

    char* ws = (char*)d_ws;
    size_t off = 0;
    auto alloc = [&](size_t bytes) {
        void* p = ws + off;
        off = (off + bytes + 255) & ~(size_t)255;
        return p;
    };
    int*   deg     = (int*)alloc(N_NODES * 4);
    int*   cnt     = (int*)alloc(N_NODES * 4);
    int*   row_ptr = (int*)alloc((N_NODES + 1) * 4);
    int*   col     = (int*)alloc(N_EDGES * 4);
    float* norm    = (float*)alloc(N_NODES * 4);
    float* f1      = (float*)alloc((size_t)N_NODES * 128 * 4);
    float* f2      = (float*)alloc((size_t)N_NODES * 128 * 4);
    float* x2      = (float*)alloc((size_t)N_NODES * 128 * 4);
    float* x3      = (float*)alloc((size_t)N_NODES * 128 * 4);
    float* gsum    = (float*)alloc(B_GRAPHS * 128 * 4);
    int*   gcnt    = (int*)alloc(B_GRAPHS * 4);

    hipMemsetAsync(deg, 0, N_NODES * 4, stream);
    hipMemsetAsync(cnt, 0, N_NODES * 4, stream);
    hipMemsetAsync(gsum, 0, B_GRAPHS * 128 * 4, stream);
    hipMemsetAsync(gcnt, 0, B_GRAPHS * 4, stream);

    k_deg<<<(N_EDGES + 255) / 256, 256, 0, stream>>>(dst, deg);
    k_norm<<<(N_NODES + 255) / 256, 256, 0, stream>>>(deg, norm);
    k_scan<<<1, 1024, 0, stream>>>(deg, row_ptr);
    k_scatter<<<(N_EDGES + 255) / 256, 256, 0, stream>>>(src, dst, row_ptr, cnt, col);

    int spmm_grid = (N_NODES + 3) / 4;
    int gemm_grid = (N_NODES + 127) / 128;

    // Layer 1: feats = [h, f1, f2]
    k_spmm<<<spmm_grid, 256, 0, stream>>>(h, norm, row_ptr, col, f1);
    k_spmm<<<spmm_grid, 256, 0, stream>>>(f1, norm, row_ptr, col, f2);
    k_gemm<<<gemm_grid, 256, 0, stream>>>(h, f1, f2, W1, b1, x2, 1);

    // Layer 2: feats = [x2, f1, f2]
    k_spmm<<<spmm_grid, 256, 0, stream>>>(x2, norm, row_ptr, col, f1);
    k_spmm<<<spmm_grid, 256, 0, stream>>>(f1, norm, row_ptr, col, f2);
    k_gemm<<<gemm_grid, 256, 0, stream>>>(x2, f1, f2, W2, b2, x3, 0);

    // Readout
    k_pool<<<(N_NODES + POOL_CH - 1) / POOL_CH, 128, 0, stream>>>(x3, gid, gsum, gcnt);
    k_final<<<1, 128, 0, stream>>>(gsum, gcnt, perm, Wc, bc, out);
}

// Round 2
// 740.774 us; speedup vs baseline: 1.0754x; 1.0754x over previous
//
#include <hip/hip_runtime.h>

#define N_NODES 50000
#define N_EDGES 600000
#define B_GRAPHS 64
#define DH 128
#define PFEAT 32
#define NCLS 2
#define SCAN_BLOCKS ((N_NODES + 255) / 256)   // 196

// ---------- degree count ----------
__global__ void k_deg(const int* __restrict__ dst, int* __restrict__ deg) {
    int e = blockIdx.x * blockDim.x + threadIdx.x;
    if (e < N_EDGES) atomicAdd(&deg[dst[e]], 1);
}

// ---------- norm = clamp(deg,1)^-0.5 ----------
__global__ void k_norm(const int* __restrict__ deg, float* __restrict__ norm) {
    int n = blockIdx.x * blockDim.x + threadIdx.x;
    if (n < N_NODES) {
        int d = deg[n];
        if (d < 1) d = 1;
        norm[n] = rsqrtf((float)d);
    }
}

// ---------- per-graph node counts ----------
__global__ void k_gcnt(const int* __restrict__ gid, int* __restrict__ gcnt) {
    int n = blockIdx.x * blockDim.x + threadIdx.x;
    if (n < N_NODES) atomicAdd(&gcnt[gid[n]], 1);
}

// ---------- multi-block scan: phase 1, per-block sums ----------
__global__ void k_bsum(const int* __restrict__ deg, int* __restrict__ bsum) {
    __shared__ int s[256];
    int i = blockIdx.x * 256 + threadIdx.x;
    s[threadIdx.x] = (i < N_NODES) ? deg[i] : 0;
    __syncthreads();
    for (int off = 128; off > 0; off >>= 1) {
        if (threadIdx.x < off) s[threadIdx.x] += s[threadIdx.x + off];
        __syncthreads();
    }
    if (threadIdx.x == 0) bsum[blockIdx.x] = s[0];
}

// ---------- phase 2: single-block exclusive scan of block sums ----------
__global__ void k_bscan(int* __restrict__ bsum) {
    __shared__ int s[256];
    int v = (threadIdx.x < SCAN_BLOCKS) ? bsum[threadIdx.x] : 0;
    s[threadIdx.x] = v;
    __syncthreads();
    for (int off = 1; off < 256; off <<= 1) {
        int t = (threadIdx.x >= off) ? s[threadIdx.x - off] : 0;
        __syncthreads();
        s[threadIdx.x] += t;
        __syncthreads();
    }
    if (threadIdx.x < SCAN_BLOCKS) bsum[threadIdx.x] = s[threadIdx.x] - v;  // exclusive
}

// ---------- phase 3: per-block inclusive scan + offset -> row_ptr ----------
__global__ void k_scan2(const int* __restrict__ deg, const int* __restrict__ bsum,
                        int* __restrict__ row_ptr) {
    __shared__ int s[256];
    int i = blockIdx.x * 256 + threadIdx.x;
    int v = (i < N_NODES) ? deg[i] : 0;
    s[threadIdx.x] = v;
    __syncthreads();
    for (int off = 1; off < 256; off <<= 1) {
        int t = (threadIdx.x >= off) ? s[threadIdx.x - off] : 0;
        __syncthreads();
        s[threadIdx.x] += t;
        __syncthreads();
    }
    if (i < N_NODES) row_ptr[i + 1] = s[threadIdx.x] + bsum[blockIdx.x];
    if (i == 0) row_ptr[0] = 0;
}

// ---------- scatter edges into CSR buckets ----------
__global__ void k_scatter(const int* __restrict__ src, const int* __restrict__ dst,
                          const int* __restrict__ row_ptr, int* __restrict__ cnt,
                          int* __restrict__ col) {
    int e = blockIdx.x * blockDim.x + threadIdx.x;
    if (e < N_EDGES) {
        int d = dst[e];
        int pos = atomicAdd(&cnt[d], 1);
        col[row_ptr[d] + pos] = src[e];
    }
}

// ---------- SpMM hop: out[v] = norm[v] * sum_{u in Nin(v)} in[u]*norm[u] ----------
__global__ __launch_bounds__(256) void k_spmm(const float* __restrict__ fin,
                                              const float* __restrict__ norm,
                                              const int* __restrict__ row_ptr,
                                              const int* __restrict__ col,
                                              float* __restrict__ fout) {
    int wave = threadIdx.x >> 6;
    int lane = threadIdx.x & 63;
    int v = blockIdx.x * 4 + wave;
    if (v >= N_NODES) return;
    int beg = row_ptr[v], end = row_ptr[v + 1];
    float2 a0 = {0.f, 0.f}, a1 = {0.f, 0.f};
    int e = beg;
    for (; e + 2 <= end; e += 2) {
        int u0 = col[e], u1 = col[e + 1];
        float w0 = norm[u0], w1 = norm[u1];
        float2 v0 = ((const float2*)(fin + (size_t)u0 * 128))[lane];
        float2 v1 = ((const float2*)(fin + (size_t)u1 * 128))[lane];
        a0.x = fmaf(v0.x, w0, a0.x);
        a0.y = fmaf(v0.y, w0, a0.y);
        a1.x = fmaf(v1.x, w1, a1.x);
        a1.y = fmaf(v1.y, w1, a1.y);
    }
    if (e < end) {
        int u = col[e];
        float w = norm[u];
        float2 v0 = ((const float2*)(fin + (size_t)u * 128))[lane];
        a0.x = fmaf(v0.x, w, a0.x);
        a0.y = fmaf(v0.y, w, a0.y);
    }
    float nv = norm[v];
    float2 res;
    res.x = (a0.x + a1.x) * nv;
    res.y = (a0.y + a1.y) * nv;
    ((float2*)(fout + (size_t)v * 128))[lane] = res;
}

// ---------- fp32 tiled GEMM: [A0|A1|A2] @ W + bias, optional relu / fused pool ----------
// A0/A1/A2: [N,128] row-major, W: [384,128] row-major
template <bool RELU, bool POOL>
__global__ __launch_bounds__(256) void k_gemm(const float* __restrict__ A0,
                                              const float* __restrict__ A1,
                                              const float* __restrict__ A2,
                                              const float* __restrict__ W,
                                              const float* __restrict__ bias,
                                              float* __restrict__ out,
                                              const int* __restrict__ gid,
                                              float* __restrict__ gsum) {
    __shared__ float As[16 * 128];
    __shared__ float Ws[16 * 128];
    int tid = threadIdx.x;
    int tx = tid & 15;   // col group 0..15
    int ty = tid >> 4;   // row group 0..15
    int n0 = blockIdx.x * 128;
    float acc[8][8] = {{0.f}};
    const float* Aseg[3] = {A0, A1, A2};
    for (int kb = 0; kb < 24; ++kb) {
        const float* A = Aseg[kb >> 3];
        int klocal = (kb & 7) * 16;
#pragma unroll
        for (int i = 0; i < 8; ++i) {
            int idx = tid + i * 256;
            int m = idx >> 4, k = idx & 15;
            int row = n0 + m;
            As[k * 128 + m] = (row < N_NODES) ? A[(size_t)row * 128 + klocal + k] : 0.f;
        }
#pragma unroll
        for (int i = 0; i < 8; ++i) {
            int idx = tid + i * 256;
            Ws[idx] = W[(size_t)kb * 16 * 128 + idx];
        }
        __syncthreads();
#pragma unroll
        for (int k = 0; k < 16; ++k) {
            float ra[8], rb[8];
#pragma unroll
            for (int i = 0; i < 8; ++i) ra[i] = As[k * 128 + ty * 8 + i];
#pragma unroll
            for (int j = 0; j < 8; ++j) rb[j] = Ws[k * 128 + tx * 8 + j];
#pragma unroll
            for (int i = 0; i < 8; ++i)
#pragma unroll
                for (int j = 0; j < 8; ++j) acc[i][j] += ra[i] * rb[j];
        }
        __syncthreads();
    }

    if (!POOL) {
#pragma unroll
        for (int i = 0; i < 8; ++i) {
            int row = n0 + ty * 8 + i;
            if (row < N_NODES) {
#pragma unroll
                for (int j = 0; j < 8; ++j) {
                    float v = acc[i][j] + bias[tx * 8 + j];
                    if (RELU) v = fmaxf(v, 0.f);
                    out[(size_t)row * 128 + tx * 8 + j] = v;
                }
            }
        }
    } else {
        // fused mean-pool numerator: segmented by sorted graph_ids
        int row0 = n0 + ty * 8;
        int gr[8];
#pragma unroll
        for (int i = 0; i < 8; ++i) {
            int r = row0 + i;
            gr[i] = (r < N_NODES) ? gid[r] : -1;
        }
        float bj[8];
#pragma unroll
        for (int j = 0; j < 8; ++j) bj[j] = bias[tx * 8 + j];
        int lastrow = n0 + 127;
        if (lastrow >= N_NODES) lastrow = N_NODES - 1;
        int gfirst = gid[n0];
        int glast = gid[lastrow];
        float(*red)[128] = (float(*)[128])As;  // reuse LDS (16x128 floats)
        for (int g = gfirst; g <= glast; ++g) {
#pragma unroll
            for (int j = 0; j < 8; ++j) {
                float s = 0.f;
#pragma unroll
                for (int i = 0; i < 8; ++i)
                    if (gr[i] == g) s += acc[i][j] + bj[j];
                red[ty][tx * 8 + j] = s;
            }
            __syncthreads();
            if (tid < 128) {
                float s = 0.f;
#pragma unroll
                for (int t = 0; t < 16; ++t) s += red[t][tid];
                atomicAdd(&gsum[g * 128 + tid], s);
            }
            __syncthreads();
        }
    }
}

// ---------- final: out[b,c] = mean(hg) @ Wc + perm @ Wc_tail + bc ----------
__global__ void k_final(const float* __restrict__ gsum, const int* __restrict__ gcnt,
                        const float* __restrict__ perm, const float* __restrict__ Wc,
                        const float* __restrict__ bc, float* __restrict__ out) {
    int t = threadIdx.x;
    if (t >= B_GRAPHS * NCLS) return;
    int b = t / NCLS, c = t % NCLS;
    float cf = (float)gcnt[b];
    if (cf < 1.f) cf = 1.f;
    float acc = bc[c];
    for (int d = 0; d < DH; ++d) acc += (gsum[b * 128 + d] / cf) * Wc[d * NCLS + c];
    for (int p = 0; p < PFEAT; ++p) acc += perm[b * PFEAT + p] * Wc[(DH + p) * NCLS + c];
    out[t] = acc;
}

extern "C" void kernel_launch(void* const* d_in, const int* in_sizes, int n_in,
                              void* d_out, int out_size, void* d_ws, size_t ws_size,
                              hipStream_t stream) {
    const float* h    = (const float*)d_in[0];
    const int*   src  = (const int*)d_in[1];
    const int*   dst  = (const int*)d_in[2];
    const int*   gid  = (const int*)d_in[3];
    const float* perm = (const float*)d_in[4];
    const float* W1   = (const float*)d_in[5];
    const float* b1   = (const float*)d_in[6];
    const float* W2   = (const float*)d_in[7];
    const float* b2   = (const float*)d_in[8];
    const float* Wc   = (const float*)d_in[9];
    const float* bc   = (const float*)d_in[10];
    float* out = (float*)d_out;

    char* ws = (char*)d_ws;
    size_t off = 0;
    auto alloc = [&](size_t bytes) {
        void* p = ws + off;
        off = (off + bytes + 255) & ~(size_t)255;
        return p;
    };
    int*   deg     = (int*)alloc(N_NODES * 4);
    int*   cnt     = (int*)alloc(N_NODES * 4);
    int*   row_ptr = (int*)alloc((N_NODES + 1) * 4);
    int*   col     = (int*)alloc(N_EDGES * 4);
    int*   bsum    = (int*)alloc(SCAN_BLOCKS * 4);
    float* norm    = (float*)alloc(N_NODES * 4);
    float* f1      = (float*)alloc((size_t)N_NODES * 128 * 4);
    float* f2      = (float*)alloc((size_t)N_NODES * 128 * 4);
    float* x2      = (float*)alloc((size_t)N_NODES * 128 * 4);
    float* gsum    = (float*)alloc(B_GRAPHS * 128 * 4);
    int*   gcnt    = (int*)alloc(B_GRAPHS * 4);

    hipMemsetAsync(deg, 0, N_NODES * 4, stream);
    hipMemsetAsync(cnt, 0, N_NODES * 4, stream);
    hipMemsetAsync(gsum, 0, B_GRAPHS * 128 * 4, stream);
    hipMemsetAsync(gcnt, 0, B_GRAPHS * 4, stream);

    k_deg<<<(N_EDGES + 255) / 256, 256, 0, stream>>>(dst, deg);
    k_norm<<<(N_NODES + 255) / 256, 256, 0, stream>>>(deg, norm);
    k_gcnt<<<(N_NODES + 255) / 256, 256, 0, stream>>>(gid, gcnt);
    k_bsum<<<SCAN_BLOCKS, 256, 0, stream>>>(deg, bsum);
    k_bscan<<<1, 256, 0, stream>>>(bsum);
    k_scan2<<<SCAN_BLOCKS, 256, 0, stream>>>(deg, bsum, row_ptr);
    k_scatter<<<(N_EDGES + 255) / 256, 256, 0, stream>>>(src, dst, row_ptr, cnt, col);

    int spmm_grid = (N_NODES + 3) / 4;
    int gemm_grid = (N_NODES + 127) / 128;

    // Layer 1: feats = [h, f1, f2] -> x2 (relu)
    k_spmm<<<spmm_grid, 256, 0, stream>>>(h, norm, row_ptr, col, f1);
    k_spmm<<<spmm_grid, 256, 0, stream>>>(f1, norm, row_ptr, col, f2);
    k_gemm<true, false><<<gemm_grid, 256, 0, stream>>>(h, f1, f2, W1, b1, x2, gid, gsum);

    // Layer 2: feats = [x2, f1, f2] -> fused mean-pool numerator
    k_spmm<<<spmm_grid, 256, 0, stream>>>(x2, norm, row_ptr, col, f1);
    k_spmm<<<spmm_grid, 256, 0, stream>>>(f1, norm, row_ptr, col, f2);
    k_gemm<false, true><<<gemm_grid, 256, 0, stream>>>(x2, f1, f2, W2, b2, nullptr, gid, gsum);

    // Readout
    k_final<<<1, 128, 0, stream>>>(gsum, gcnt, perm, Wc, bc, out);
}

// Round 3
// 507.642 us; speedup vs baseline: 1.5692x; 1.4592x over previous
//
#include <hip/hip_runtime.h>

#define N_NODES 50000
#define N_EDGES 600000
#define B_GRAPHS 64
#define DH 128
#define PFEAT 32
#define NCLS 2
#define SCAN_BLOCKS ((N_NODES + 255) / 256)   // 196

// ---------- degree count ----------
__global__ void k_deg(const int* __restrict__ dst, int* __restrict__ deg) {
    int e = blockIdx.x * blockDim.x + threadIdx.x;
    if (e < N_EDGES) atomicAdd(&deg[dst[e]], 1);
}

// ---------- norm = clamp(deg,1)^-0.5 ----------
__global__ void k_norm(const int* __restrict__ deg, float* __restrict__ norm) {
    int n = blockIdx.x * blockDim.x + threadIdx.x;
    if (n < N_NODES) {
        int d = deg[n];
        if (d < 1) d = 1;
        norm[n] = rsqrtf((float)d);
    }
}

// ---------- graph run-starts (gid is sorted; no atomics) ----------
__global__ void k_bound(const int* __restrict__ gid, int* __restrict__ gstart) {
    int n = blockIdx.x * blockDim.x + threadIdx.x;
    if (n < N_NODES) {
        int g = gid[n];
        if (n == 0 || gid[n - 1] != g) gstart[g] = n;
    }
}

// ---------- multi-block scan: phase 1, per-block sums ----------
__global__ void k_bsum(const int* __restrict__ deg, int* __restrict__ bsum) {
    __shared__ int s[256];
    int i = blockIdx.x * 256 + threadIdx.x;
    s[threadIdx.x] = (i < N_NODES) ? deg[i] : 0;
    __syncthreads();
    for (int off = 128; off > 0; off >>= 1) {
        if (threadIdx.x < off) s[threadIdx.x] += s[threadIdx.x + off];
        __syncthreads();
    }
    if (threadIdx.x == 0) bsum[blockIdx.x] = s[0];
}

// ---------- phase 2: single-block exclusive scan of block sums ----------
__global__ void k_bscan(int* __restrict__ bsum) {
    __shared__ int s[256];
    int v = (threadIdx.x < SCAN_BLOCKS) ? bsum[threadIdx.x] : 0;
    s[threadIdx.x] = v;
    __syncthreads();
    for (int off = 1; off < 256; off <<= 1) {
        int t = (threadIdx.x >= off) ? s[threadIdx.x - off] : 0;
        __syncthreads();
        s[threadIdx.x] += t;
        __syncthreads();
    }
    if (threadIdx.x < SCAN_BLOCKS) bsum[threadIdx.x] = s[threadIdx.x] - v;  // exclusive
}

// ---------- phase 3: per-block inclusive scan + offset -> row_ptr ----------
__global__ void k_scan2(const int* __restrict__ deg, const int* __restrict__ bsum,
                        int* __restrict__ row_ptr) {
    __shared__ int s[256];
    int i = blockIdx.x * 256 + threadIdx.x;
    int v = (i < N_NODES) ? deg[i] : 0;
    s[threadIdx.x] = v;
    __syncthreads();
    for (int off = 1; off < 256; off <<= 1) {
        int t = (threadIdx.x >= off) ? s[threadIdx.x - off] : 0;
        __syncthreads();
        s[threadIdx.x] += t;
        __syncthreads();
    }
    if (i < N_NODES) row_ptr[i + 1] = s[threadIdx.x] + bsum[blockIdx.x];
    if (i == 0) row_ptr[0] = 0;
}

// ---------- scatter edges into CSR buckets ----------
__global__ void k_scatter(const int* __restrict__ src, const int* __restrict__ dst,
                          const int* __restrict__ row_ptr, int* __restrict__ cnt,
                          int* __restrict__ col) {
    int e = blockIdx.x * blockDim.x + threadIdx.x;
    if (e < N_EDGES) {
        int d = dst[e];
        int pos = atomicAdd(&cnt[d], 1);
        col[row_ptr[d] + pos] = src[e];
    }
}

// ---------- SpMM hop: out[v] = norm[v] * sum_{u in Nin(v)} in[u]*norm[u] ----------
__global__ __launch_bounds__(256) void k_spmm(const float* __restrict__ fin,
                                              const float* __restrict__ norm,
                                              const int* __restrict__ row_ptr,
                                              const int* __restrict__ col,
                                              float* __restrict__ fout) {
    int wave = threadIdx.x >> 6;
    int lane = threadIdx.x & 63;
    int v = blockIdx.x * 4 + wave;
    if (v >= N_NODES) return;
    int beg = row_ptr[v], end = row_ptr[v + 1];
    float2 a0 = {0.f, 0.f}, a1 = {0.f, 0.f};
    int e = beg;
    for (; e + 2 <= end; e += 2) {
        int u0 = col[e], u1 = col[e + 1];
        float w0 = norm[u0], w1 = norm[u1];
        float2 v0 = ((const float2*)(fin + (size_t)u0 * 128))[lane];
        float2 v1 = ((const float2*)(fin + (size_t)u1 * 128))[lane];
        a0.x = fmaf(v0.x, w0, a0.x);
        a0.y = fmaf(v0.y, w0, a0.y);
        a1.x = fmaf(v1.x, w1, a1.x);
        a1.y = fmaf(v1.y, w1, a1.y);
    }
    if (e < end) {
        int u = col[e];
        float w = norm[u];
        float2 v0 = ((const float2*)(fin + (size_t)u * 128))[lane];
        a0.x = fmaf(v0.x, w, a0.x);
        a0.y = fmaf(v0.y, w, a0.y);
    }
    float nv = norm[v];
    float2 res;
    res.x = (a0.x + a1.x) * nv;
    res.y = (a0.y + a1.y) * nv;
    ((float2*)(fout + (size_t)v * 128))[lane] = res;
}

// ---------- fp32 tiled GEMM: [A0|A1|A2] @ W + bias, optional relu / fused pool ----------
// A0/A1/A2: [N,128] row-major, W: [384,128] row-major
template <bool RELU, bool POOL>
__global__ __launch_bounds__(256) void k_gemm(const float* __restrict__ A0,
                                              const float* __restrict__ A1,
                                              const float* __restrict__ A2,
                                              const float* __restrict__ W,
                                              const float* __restrict__ bias,
                                              float* __restrict__ out,
                                              const int* __restrict__ gid,
                                              float* __restrict__ gsum) {
    __shared__ float As[16 * 128];
    __shared__ float Ws[16 * 128];
    int tid = threadIdx.x;
    int tx = tid & 15;   // col group 0..15
    int ty = tid >> 4;   // row group 0..15
    int n0 = blockIdx.x * 128;
    float acc[8][8] = {{0.f}};
    const float* Aseg[3] = {A0, A1, A2};
    for (int kb = 0; kb < 24; ++kb) {
        const float* A = Aseg[kb >> 3];
        int klocal = (kb & 7) * 16;
#pragma unroll
        for (int i = 0; i < 8; ++i) {
            int idx = tid + i * 256;
            int m = idx >> 4, k = idx & 15;
            int row = n0 + m;
            As[k * 128 + m] = (row < N_NODES) ? A[(size_t)row * 128 + klocal + k] : 0.f;
        }
#pragma unroll
        for (int i = 0; i < 8; ++i) {
            int idx = tid + i * 256;
            Ws[idx] = W[(size_t)kb * 16 * 128 + idx];
        }
        __syncthreads();
#pragma unroll
        for (int k = 0; k < 16; ++k) {
            float ra[8], rb[8];
#pragma unroll
            for (int i = 0; i < 8; ++i) ra[i] = As[k * 128 + ty * 8 + i];
#pragma unroll
            for (int j = 0; j < 8; ++j) rb[j] = Ws[k * 128 + tx * 8 + j];
#pragma unroll
            for (int i = 0; i < 8; ++i)
#pragma unroll
                for (int j = 0; j < 8; ++j) acc[i][j] += ra[i] * rb[j];
        }
        __syncthreads();
    }

    if (!POOL) {
#pragma unroll
        for (int i = 0; i < 8; ++i) {
            int row = n0 + ty * 8 + i;
            if (row < N_NODES) {
#pragma unroll
                for (int j = 0; j < 8; ++j) {
                    float v = acc[i][j] + bias[tx * 8 + j];
                    if (RELU) v = fmaxf(v, 0.f);
                    out[(size_t)row * 128 + tx * 8 + j] = v;
                }
            }
        }
    } else {
        // fused mean-pool numerator: segmented by sorted graph_ids
        int row0 = n0 + ty * 8;
        int gr[8];
#pragma unroll
        for (int i = 0; i < 8; ++i) {
            int r = row0 + i;
            gr[i] = (r < N_NODES) ? gid[r] : -1;
        }
        float bj[8];
#pragma unroll
        for (int j = 0; j < 8; ++j) bj[j] = bias[tx * 8 + j];
        int lastrow = n0 + 127;
        if (lastrow >= N_NODES) lastrow = N_NODES - 1;
        int gfirst = gid[n0];
        int glast = gid[lastrow];
        float(*red)[128] = (float(*)[128])As;  // reuse LDS (16x128 floats)
        for (int g = gfirst; g <= glast; ++g) {
#pragma unroll
            for (int j = 0; j < 8; ++j) {
                float s = 0.f;
#pragma unroll
                for (int i = 0; i < 8; ++i)
                    if (gr[i] == g) s += acc[i][j] + bj[j];
                red[ty][tx * 8 + j] = s;
            }
            __syncthreads();
            if (tid < 128) {
                float s = 0.f;
#pragma unroll
                for (int t = 0; t < 16; ++t) s += red[t][tid];
                atomicAdd(&gsum[g * 128 + tid], s);
            }
            __syncthreads();
        }
    }
}

// ---------- final: derive counts from run-starts; out = mean @ Wc + perm @ Wc_tail + bc ----------
__global__ void k_final(const float* __restrict__ gsum, const int* __restrict__ gstart,
                        const float* __restrict__ perm, const float* __restrict__ Wc,
                        const float* __restrict__ bc, float* __restrict__ out) {
    int t = threadIdx.x;
    if (t >= B_GRAPHS * NCLS) return;
    int b = t / NCLS, c = t % NCLS;
    int s = gstart[b];
    float cf = 1.f;
    if (s >= 0) {
        int nxt = N_NODES;
        for (int j = b + 1; j < B_GRAPHS; ++j) {
            int sj = gstart[j];
            if (sj >= 0) { nxt = sj; break; }
        }
        int cnt = nxt - s;
        cf = (cnt < 1) ? 1.f : (float)cnt;
    }
    float acc = bc[c];
    for (int d = 0; d < DH; ++d) acc += (gsum[b * 128 + d] / cf) * Wc[d * NCLS + c];
    for (int p = 0; p < PFEAT; ++p) acc += perm[b * PFEAT + p] * Wc[(DH + p) * NCLS + c];
    out[t] = acc;
}

extern "C" void kernel_launch(void* const* d_in, const int* in_sizes, int n_in,
                              void* d_out, int out_size, void* d_ws, size_t ws_size,
                              hipStream_t stream) {
    const float* h    = (const float*)d_in[0];
    const int*   src  = (const int*)d_in[1];
    const int*   dst  = (const int*)d_in[2];
    const int*   gid  = (const int*)d_in[3];
    const float* perm = (const float*)d_in[4];
    const float* W1   = (const float*)d_in[5];
    const float* b1   = (const float*)d_in[6];
    const float* W2   = (const float*)d_in[7];
    const float* b2   = (const float*)d_in[8];
    const float* Wc   = (const float*)d_in[9];
    const float* bc   = (const float*)d_in[10];
    float* out = (float*)d_out;

    char* ws = (char*)d_ws;
    size_t off = 0;
    auto alloc = [&](size_t bytes) {
        void* p = ws + off;
        off = (off + bytes + 255) & ~(size_t)255;
        return p;
    };
    int*   deg     = (int*)alloc(N_NODES * 4);
    int*   cnt     = (int*)alloc(N_NODES * 4);
    int*   row_ptr = (int*)alloc((N_NODES + 1) * 4);
    int*   col     = (int*)alloc(N_EDGES * 4);
    int*   bsum    = (int*)alloc(SCAN_BLOCKS * 4);
    float* norm    = (float*)alloc(N_NODES * 4);
    float* f1      = (float*)alloc((size_t)N_NODES * 128 * 4);
    float* f2      = (float*)alloc((size_t)N_NODES * 128 * 4);
    float* x2      = (float*)alloc((size_t)N_NODES * 128 * 4);
    float* gsum    = (float*)alloc(B_GRAPHS * 128 * 4);
    int*   gstart  = (int*)alloc(B_GRAPHS * 4);

    hipMemsetAsync(deg, 0, N_NODES * 4, stream);
    hipMemsetAsync(cnt, 0, N_NODES * 4, stream);
    hipMemsetAsync(gsum, 0, B_GRAPHS * 128 * 4, stream);
    hipMemsetAsync(gstart, 0xFF, B_GRAPHS * 4, stream);  // -1 sentinel

    k_deg<<<(N_EDGES + 255) / 256, 256, 0, stream>>>(dst, deg);
    k_norm<<<(N_NODES + 255) / 256, 256, 0, stream>>>(deg, norm);
    k_bound<<<(N_NODES + 255) / 256, 256, 0, stream>>>(gid, gstart);
    k_bsum<<<SCAN_BLOCKS, 256, 0, stream>>>(deg, bsum);
    k_bscan<<<1, 256, 0, stream>>>(bsum);
    k_scan2<<<SCAN_BLOCKS, 256, 0, stream>>>(deg, bsum, row_ptr);
    k_scatter<<<(N_EDGES + 255) / 256, 256, 0, stream>>>(src, dst, row_ptr, cnt, col);

    int spmm_grid = (N_NODES + 3) / 4;
    int gemm_grid = (N_NODES + 127) / 128;

    // Layer 1: feats = [h, f1, f2] -> x2 (relu)
    k_spmm<<<spmm_grid, 256, 0, stream>>>(h, norm, row_ptr, col, f1);
    k_spmm<<<spmm_grid, 256, 0, stream>>>(f1, norm, row_ptr, col, f2);
    k_gemm<true, false><<<gemm_grid, 256, 0, stream>>>(h, f1, f2, W1, b1, x2, gid, gsum);

    // Layer 2: feats = [x2, f1, f2] -> fused mean-pool numerator
    k_spmm<<<spmm_grid, 256, 0, stream>>>(x2, norm, row_ptr, col, f1);
    k_spmm<<<spmm_grid, 256, 0, stream>>>(f1, norm, row_ptr, col, f2);
    k_gemm<false, true><<<gemm_grid, 256, 0, stream>>>(x2, f1, f2, W2, b2, nullptr, gid, gsum);

    // Readout
    k_final<<<1, 128, 0, stream>>>(gsum, gstart, perm, Wc, bc, out);
}

// Round 4
// 337.614 us; speedup vs baseline: 2.3595x; 1.5036x over previous
//
#include <hip/hip_runtime.h>

#define N_NODES 50000
#define N_EDGES 600000
#define B_GRAPHS 64
#define DH 128
#define PFEAT 32
#define NCLS 2
#define SCAN_BLOCKS ((N_NODES + 255) / 256)   // 196
#define NPAD (N_NODES + 128)                  // row padding for OOB-safe MFMA loads

typedef __attribute__((ext_vector_type(8))) short short8v;
typedef __attribute__((ext_vector_type(4))) float float4v;

__device__ __forceinline__ unsigned int f2bf(float f) {
    unsigned int u = __float_as_uint(f);
    return (u + 0x7FFFu + ((u >> 16) & 1u)) >> 16;   // RNE
}
__device__ __forceinline__ float bflo(unsigned int p) { return __uint_as_float(p << 16); }
__device__ __forceinline__ float bfhi(unsigned int p) { return __uint_as_float(p & 0xFFFF0000u); }

// ---------- fp32 -> bf16 bulk convert (4 elems/thread) ----------
__global__ void k_cvt(const float* __restrict__ in, unsigned short* __restrict__ outb, int n4) {
    int t = blockIdx.x * blockDim.x + threadIdx.x;
    if (t < n4) {
        float4 v = ((const float4*)in)[t];
        unsigned int lo = f2bf(v.x) | (f2bf(v.y) << 16);
        unsigned int hi = f2bf(v.z) | (f2bf(v.w) << 16);
        uint2 r; r.x = lo; r.y = hi;
        ((uint2*)outb)[t] = r;
    }
}

// ---------- W [384][128] fp32 -> Wt [128][384] bf16 (transposed) ----------
__global__ void k_cvt_w(const float* __restrict__ W, unsigned short* __restrict__ Wt) {
    int t = blockIdx.x * blockDim.x + threadIdx.x;
    if (t < 384 * 128) {
        int k = t >> 7, c = t & 127;
        Wt[c * 384 + k] = (unsigned short)f2bf(W[t]);
    }
}

// ---------- degree count ----------
__global__ void k_deg(const int* __restrict__ dst, int* __restrict__ deg) {
    int e = blockIdx.x * blockDim.x + threadIdx.x;
    if (e < N_EDGES) atomicAdd(&deg[dst[e]], 1);
}

// ---------- norm = clamp(deg,1)^-0.5 ----------
__global__ void k_norm(const int* __restrict__ deg, float* __restrict__ norm) {
    int n = blockIdx.x * blockDim.x + threadIdx.x;
    if (n < N_NODES) {
        int d = deg[n];
        if (d < 1) d = 1;
        norm[n] = rsqrtf((float)d);
    }
}

// ---------- graph run-starts (gid sorted; no atomics) ----------
__global__ void k_bound(const int* __restrict__ gid, int* __restrict__ gstart) {
    int n = blockIdx.x * blockDim.x + threadIdx.x;
    if (n < N_NODES) {
        int g = gid[n];
        if (n == 0 || gid[n - 1] != g) gstart[g] = n;
    }
}

// ---------- multi-block scan ----------
__global__ void k_bsum(const int* __restrict__ deg, int* __restrict__ bsum) {
    __shared__ int s[256];
    int i = blockIdx.x * 256 + threadIdx.x;
    s[threadIdx.x] = (i < N_NODES) ? deg[i] : 0;
    __syncthreads();
    for (int off = 128; off > 0; off >>= 1) {
        if (threadIdx.x < off) s[threadIdx.x] += s[threadIdx.x + off];
        __syncthreads();
    }
    if (threadIdx.x == 0) bsum[blockIdx.x] = s[0];
}

__global__ void k_bscan(int* __restrict__ bsum) {
    __shared__ int s[256];
    int v = (threadIdx.x < SCAN_BLOCKS) ? bsum[threadIdx.x] : 0;
    s[threadIdx.x] = v;
    __syncthreads();
    for (int off = 1; off < 256; off <<= 1) {
        int t = (threadIdx.x >= off) ? s[threadIdx.x - off] : 0;
        __syncthreads();
        s[threadIdx.x] += t;
        __syncthreads();
    }
    if (threadIdx.x < SCAN_BLOCKS) bsum[threadIdx.x] = s[threadIdx.x] - v;
}

__global__ void k_scan2(const int* __restrict__ deg, const int* __restrict__ bsum,
                        int* __restrict__ row_ptr) {
    __shared__ int s[256];
    int i = blockIdx.x * 256 + threadIdx.x;
    int v = (i < N_NODES) ? deg[i] : 0;
    s[threadIdx.x] = v;
    __syncthreads();
    for (int off = 1; off < 256; off <<= 1) {
        int t = (threadIdx.x >= off) ? s[threadIdx.x - off] : 0;
        __syncthreads();
        s[threadIdx.x] += t;
        __syncthreads();
    }
    if (i < N_NODES) row_ptr[i + 1] = s[threadIdx.x] + bsum[blockIdx.x];
    if (i == 0) row_ptr[0] = 0;
}

// ---------- scatter edges into CSR buckets ----------
__global__ void k_scatter(const int* __restrict__ src, const int* __restrict__ dst,
                          const int* __restrict__ row_ptr, int* __restrict__ cnt,
                          int* __restrict__ col) {
    int e = blockIdx.x * blockDim.x + threadIdx.x;
    if (e < N_EDGES) {
        int d = dst[e];
        int pos = atomicAdd(&cnt[d], 1);
        col[row_ptr[d] + pos] = src[e];
    }
}

// ---------- SpMM hop (bf16 in / bf16 out, fp32 accumulate) ----------
__global__ __launch_bounds__(256) void k_spmm(const unsigned short* __restrict__ fin,
                                              const float* __restrict__ norm,
                                              const int* __restrict__ row_ptr,
                                              const int* __restrict__ col,
                                              unsigned short* __restrict__ fout) {
    int wave = threadIdx.x >> 6;
    int lane = threadIdx.x & 63;
    int v = blockIdx.x * 4 + wave;
    if (v >= N_NODES) return;
    int beg = row_ptr[v], end = row_ptr[v + 1];
    float ax0 = 0.f, ay0 = 0.f, ax1 = 0.f, ay1 = 0.f;
    int e = beg;
    for (; e + 2 <= end; e += 2) {
        int u0 = col[e], u1 = col[e + 1];
        float w0 = norm[u0], w1 = norm[u1];
        unsigned int p0 = *(const unsigned int*)(fin + (size_t)u0 * 128 + lane * 2);
        unsigned int p1 = *(const unsigned int*)(fin + (size_t)u1 * 128 + lane * 2);
        ax0 = fmaf(bflo(p0), w0, ax0);
        ay0 = fmaf(bfhi(p0), w0, ay0);
        ax1 = fmaf(bflo(p1), w1, ax1);
        ay1 = fmaf(bfhi(p1), w1, ay1);
    }
    if (e < end) {
        int u = col[e];
        float w = norm[u];
        unsigned int p = *(const unsigned int*)(fin + (size_t)u * 128 + lane * 2);
        ax0 = fmaf(bflo(p), w, ax0);
        ay0 = fmaf(bfhi(p), w, ay0);
    }
    float nv = norm[v];
    float rx = (ax0 + ax1) * nv;
    float ry = (ay0 + ay1) * nv;
    unsigned int packed = f2bf(rx) | (f2bf(ry) << 16);
    *(unsigned int*)(fout + (size_t)v * 128 + lane * 2) = packed;
}

// ---------- bf16 MFMA GEMM: [A0|A1|A2] @ W(+bias), relu-store or fused pool ----------
// A0/A1/A2: [NPAD][128] bf16 row-major. Wt: [128 cols][384 k] bf16.
// Block = 256 thr = 4 waves; wave handles 32 rows x 128 cols (2x8 16x16 tiles).
template <bool RELU, bool POOL>
__global__ __launch_bounds__(256) void k_gemm_mfma(const unsigned short* __restrict__ A0,
                                                   const unsigned short* __restrict__ A1,
                                                   const unsigned short* __restrict__ A2,
                                                   const unsigned short* __restrict__ Wt,
                                                   const float* __restrict__ bias,
                                                   unsigned short* __restrict__ out,
                                                   const int* __restrict__ gid,
                                                   float* __restrict__ gsum) {
    __shared__ float red4[4][128];
    int tid = threadIdx.x;
    int lane = tid & 63;
    int wid = tid >> 6;
    int l15 = lane & 15;
    int lk = lane >> 4;                 // 0..3
    int n0 = blockIdx.x * 128;
    int rbase = n0 + wid * 32;

    float4v acc[2][8];
#pragma unroll
    for (int rt = 0; rt < 2; ++rt)
#pragma unroll
        for (int ct = 0; ct < 8; ++ct)
#pragma unroll
            for (int i = 0; i < 4; ++i) acc[rt][ct][i] = 0.f;

    const unsigned short* Aseg[3] = {A0, A1, A2};
#pragma unroll
    for (int ks = 0; ks < 12; ++ks) {
        const unsigned short* A = Aseg[ks >> 2];
        int kloc = (ks & 3) * 32 + lk * 8;
        short8v a0 = *(const short8v*)(A + (size_t)(rbase + l15) * 128 + kloc);
        short8v a1 = *(const short8v*)(A + (size_t)(rbase + 16 + l15) * 128 + kloc);
        const unsigned short* wp = Wt + (size_t)l15 * 384 + ks * 32 + lk * 8;
#pragma unroll
        for (int ct = 0; ct < 8; ++ct) {
            short8v b = *(const short8v*)(wp + (size_t)ct * 16 * 384);
            acc[0][ct] = __builtin_amdgcn_mfma_f32_16x16x32_bf16(a0, b, acc[0][ct], 0, 0, 0);
            acc[1][ct] = __builtin_amdgcn_mfma_f32_16x16x32_bf16(a1, b, acc[1][ct], 0, 0, 0);
        }
    }

    if (!POOL) {
        // epilogue: + bias, relu, bf16 store. C/D: col=lane&15, row=(lane>>4)*4+reg
        float bj[8];
#pragma unroll
        for (int ct = 0; ct < 8; ++ct) bj[ct] = bias[ct * 16 + l15];
#pragma unroll
        for (int rt = 0; rt < 2; ++rt)
#pragma unroll
            for (int i = 0; i < 4; ++i) {
                int row = rbase + rt * 16 + lk * 4 + i;
                if (row < N_NODES) {
#pragma unroll
                    for (int ct = 0; ct < 8; ++ct) {
                        float v = acc[rt][ct][i] + bj[ct];
                        if (RELU) v = fmaxf(v, 0.f);
                        out[(size_t)row * 128 + ct * 16 + l15] = (unsigned short)f2bf(v);
                    }
                }
            }
    } else {
        // fused mean-pool numerator (bias deferred to k_final)
        int gr[2][4];
#pragma unroll
        for (int rt = 0; rt < 2; ++rt)
#pragma unroll
            for (int i = 0; i < 4; ++i) {
                int row = rbase + rt * 16 + lk * 4 + i;
                gr[rt][i] = (row < N_NODES) ? gid[row] : -1;
            }
        int lastrow = n0 + 127;
        if (lastrow >= N_NODES) lastrow = N_NODES - 1;
        int gfirst = gid[n0];
        int glast = gid[lastrow];
        for (int g = gfirst; g <= glast; ++g) {
            float p[8];
#pragma unroll
            for (int ct = 0; ct < 8; ++ct) {
                float s = 0.f;
#pragma unroll
                for (int rt = 0; rt < 2; ++rt)
#pragma unroll
                    for (int i = 0; i < 4; ++i)
                        if (gr[rt][i] == g) s += acc[rt][ct][i];
                p[ct] = s;
            }
            // reduce across the 4 k-groups (lanes ^16, ^32 hold same col)
#pragma unroll
            for (int ct = 0; ct < 8; ++ct) {
                p[ct] += __shfl_xor(p[ct], 16, 64);
                p[ct] += __shfl_xor(p[ct], 32, 64);
            }
            if (lane < 16) {
#pragma unroll
                for (int ct = 0; ct < 8; ++ct) red4[wid][ct * 16 + lane] = p[ct];
            }
            __syncthreads();
            if (tid < 128) {
                float s = red4[0][tid] + red4[1][tid] + red4[2][tid] + red4[3][tid];
                atomicAdd(&gsum[g * 128 + tid], s);
            }
            __syncthreads();
        }
    }
}

// ---------- final: counts from run-starts; combined = gsum/cnt + b2 ; out = @Wc + bc ----------
__global__ void k_final(const float* __restrict__ gsum, const int* __restrict__ gstart,
                        const float* __restrict__ b2, const float* __restrict__ perm,
                        const float* __restrict__ Wc, const float* __restrict__ bc,
                        float* __restrict__ out) {
    int t = threadIdx.x;
    if (t >= B_GRAPHS * NCLS) return;
    int b = t / NCLS, c = t % NCLS;
    int s = gstart[b];
    float cf = 1.f;
    bool nonempty = (s >= 0);
    if (nonempty) {
        int nxt = N_NODES;
        for (int j = b + 1; j < B_GRAPHS; ++j) {
            int sj = gstart[j];
            if (sj >= 0) { nxt = sj; break; }
        }
        int cnt = nxt - s;
        cf = (cnt < 1) ? 1.f : (float)cnt;
    }
    float acc = bc[c];
    for (int d = 0; d < DH; ++d) {
        float hg = gsum[b * 128 + d] / cf + (nonempty ? b2[d] : 0.f);
        acc += hg * Wc[d * NCLS + c];
    }
    for (int p = 0; p < PFEAT; ++p) acc += perm[b * PFEAT + p] * Wc[(DH + p) * NCLS + c];
    out[t] = acc;
}

extern "C" void kernel_launch(void* const* d_in, const int* in_sizes, int n_in,
                              void* d_out, int out_size, void* d_ws, size_t ws_size,
                              hipStream_t stream) {
    const float* h    = (const float*)d_in[0];
    const int*   src  = (const int*)d_in[1];
    const int*   dst  = (const int*)d_in[2];
    const int*   gid  = (const int*)d_in[3];
    const float* perm = (const float*)d_in[4];
    const float* W1   = (const float*)d_in[5];
    const float* b1   = (const float*)d_in[6];
    const float* W2   = (const float*)d_in[7];
    const float* b2   = (const float*)d_in[8];
    const float* Wc   = (const float*)d_in[9];
    const float* bc   = (const float*)d_in[10];
    float* out = (float*)d_out;

    char* ws = (char*)d_ws;
    size_t off = 0;
    auto alloc = [&](size_t bytes) {
        void* p = ws + off;
        off = (off + bytes + 255) & ~(size_t)255;
        return p;
    };
    int*   deg     = (int*)alloc(N_NODES * 4);
    int*   cnt     = (int*)alloc(N_NODES * 4);
    int*   row_ptr = (int*)alloc((N_NODES + 1) * 4);
    int*   col     = (int*)alloc(N_EDGES * 4);
    int*   bsum    = (int*)alloc(SCAN_BLOCKS * 4);
    float* norm    = (float*)alloc(N_NODES * 4);
    unsigned short* h_bf = (unsigned short*)alloc((size_t)NPAD * 128 * 2);
    unsigned short* f1   = (unsigned short*)alloc((size_t)NPAD * 128 * 2);
    unsigned short* f2   = (unsigned short*)alloc((size_t)NPAD * 128 * 2);
    unsigned short* x2   = (unsigned short*)alloc((size_t)NPAD * 128 * 2);
    unsigned short* Wt1  = (unsigned short*)alloc(384 * 128 * 2);
    unsigned short* Wt2  = (unsigned short*)alloc(384 * 128 * 2);
    float* gsum    = (float*)alloc(B_GRAPHS * 128 * 4);
    int*   gstart  = (int*)alloc(B_GRAPHS * 4);

    hipMemsetAsync(deg, 0, N_NODES * 4, stream);
    hipMemsetAsync(cnt, 0, N_NODES * 4, stream);
    hipMemsetAsync(gsum, 0, B_GRAPHS * 128 * 4, stream);
    hipMemsetAsync(gstart, 0xFF, B_GRAPHS * 4, stream);  // -1 sentinel

    // dtype prep
    k_cvt<<<(N_NODES * 128 / 4 + 255) / 256, 256, 0, stream>>>(h, h_bf, N_NODES * 128 / 4);
    k_cvt_w<<<(384 * 128 + 255) / 256, 256, 0, stream>>>(W1, Wt1);
    k_cvt_w<<<(384 * 128 + 255) / 256, 256, 0, stream>>>(W2, Wt2);

    // CSR build
    k_deg<<<(N_EDGES + 255) / 256, 256, 0, stream>>>(dst, deg);
    k_norm<<<(N_NODES + 255) / 256, 256, 0, stream>>>(deg, norm);
    k_bound<<<(N_NODES + 255) / 256, 256, 0, stream>>>(gid, gstart);
    k_bsum<<<SCAN_BLOCKS, 256, 0, stream>>>(deg, bsum);
    k_bscan<<<1, 256, 0, stream>>>(bsum);
    k_scan2<<<SCAN_BLOCKS, 256, 0, stream>>>(deg, bsum, row_ptr);
    k_scatter<<<(N_EDGES + 255) / 256, 256, 0, stream>>>(src, dst, row_ptr, cnt, col);

    int spmm_grid = (N_NODES + 3) / 4;
    int gemm_grid = (N_NODES + 127) / 128;

    // Layer 1: feats = [h, f1, f2] -> x2 (relu, bf16)
    k_spmm<<<spmm_grid, 256, 0, stream>>>(h_bf, norm, row_ptr, col, f1);
    k_spmm<<<spmm_grid, 256, 0, stream>>>(f1, norm, row_ptr, col, f2);
    k_gemm_mfma<true, false><<<gemm_grid, 256, 0, stream>>>(h_bf, f1, f2, Wt1, b1, x2, gid, gsum);

    // Layer 2: feats = [x2, f1, f2] -> fused mean-pool numerator
    k_spmm<<<spmm_grid, 256, 0, stream>>>(x2, norm, row_ptr, col, f1);
    k_spmm<<<spmm_grid, 256, 0, stream>>>(f1, norm, row_ptr, col, f2);
    k_gemm_mfma<false, true><<<gemm_grid, 256, 0, stream>>>(x2, f1, f2, Wt2, nullptr, nullptr, gid, gsum);

    // Readout
    k_final<<<1, 128, 0, stream>>>(gsum, gstart, b2, perm, Wc, bc, out);
}

// Round 5
// 278.521 us; speedup vs baseline: 2.8602x; 1.2122x over previous
//
#include <hip/hip_runtime.h>

#define N_NODES 50000
#define N_EDGES 600000
#define B_GRAPHS 64
#define DH 128
#define PFEAT 32
#define NCLS 2
#define SCAN_BLOCKS ((N_NODES + 255) / 256)   // 196
#define NPAD (N_NODES + 128)                  // row padding for OOB-safe MFMA loads

typedef __attribute__((ext_vector_type(8))) short short8v;
typedef __attribute__((ext_vector_type(4))) float float4v;
typedef __attribute__((ext_vector_type(4))) unsigned int uint4v;

__device__ __forceinline__ unsigned int f2bf(float f) {
    unsigned int u = __float_as_uint(f);
    return (u + 0x7FFFu + ((u >> 16) & 1u)) >> 16;   // RNE
}
__device__ __forceinline__ float bflo(unsigned int p) { return __uint_as_float(p << 16); }
__device__ __forceinline__ float bfhi(unsigned int p) { return __uint_as_float(p & 0xFFFF0000u); }

// ---------- fp32 -> bf16 bulk convert (4 elems/thread) ----------
__global__ void k_cvt(const float* __restrict__ in, unsigned short* __restrict__ outb, int n4) {
    int t = blockIdx.x * blockDim.x + threadIdx.x;
    if (t < n4) {
        float4 v = ((const float4*)in)[t];
        unsigned int lo = f2bf(v.x) | (f2bf(v.y) << 16);
        unsigned int hi = f2bf(v.z) | (f2bf(v.w) << 16);
        uint2 r; r.x = lo; r.y = hi;
        ((uint2*)outb)[t] = r;
    }
}

// ---------- W [384][128] fp32 -> Wt [128][384] bf16 (transposed) ----------
__global__ void k_cvt_w(const float* __restrict__ W, unsigned short* __restrict__ Wt) {
    int t = blockIdx.x * blockDim.x + threadIdx.x;
    if (t < 384 * 128) {
        int k = t >> 7, c = t & 127;
        Wt[c * 384 + k] = (unsigned short)f2bf(W[t]);
    }
}

// ---------- degree count ----------
__global__ void k_deg(const int* __restrict__ dst, int* __restrict__ deg) {
    int e = blockIdx.x * blockDim.x + threadIdx.x;
    if (e < N_EDGES) atomicAdd(&deg[dst[e]], 1);
}

// ---------- norm = clamp(deg,1)^-0.5 ----------
__global__ void k_norm(const int* __restrict__ deg, float* __restrict__ norm) {
    int n = blockIdx.x * blockDim.x + threadIdx.x;
    if (n < N_NODES) {
        int d = deg[n];
        if (d < 1) d = 1;
        norm[n] = rsqrtf((float)d);
    }
}

// ---------- graph run-starts (gid sorted; no atomics) ----------
__global__ void k_bound(const int* __restrict__ gid, int* __restrict__ gstart) {
    int n = blockIdx.x * blockDim.x + threadIdx.x;
    if (n < N_NODES) {
        int g = gid[n];
        if (n == 0 || gid[n - 1] != g) gstart[g] = n;
    }
}

// ---------- multi-block scan ----------
__global__ void k_bsum(const int* __restrict__ deg, int* __restrict__ bsum) {
    __shared__ int s[256];
    int i = blockIdx.x * 256 + threadIdx.x;
    s[threadIdx.x] = (i < N_NODES) ? deg[i] : 0;
    __syncthreads();
    for (int off = 128; off > 0; off >>= 1) {
        if (threadIdx.x < off) s[threadIdx.x] += s[threadIdx.x + off];
        __syncthreads();
    }
    if (threadIdx.x == 0) bsum[blockIdx.x] = s[0];
}

__global__ void k_bscan(int* __restrict__ bsum) {
    __shared__ int s[256];
    int v = (threadIdx.x < SCAN_BLOCKS) ? bsum[threadIdx.x] : 0;
    s[threadIdx.x] = v;
    __syncthreads();
    for (int off = 1; off < 256; off <<= 1) {
        int t = (threadIdx.x >= off) ? s[threadIdx.x - off] : 0;
        __syncthreads();
        s[threadIdx.x] += t;
        __syncthreads();
    }
    if (threadIdx.x < SCAN_BLOCKS) bsum[threadIdx.x] = s[threadIdx.x] - v;
}

__global__ void k_scan2(const int* __restrict__ deg, const int* __restrict__ bsum,
                        int* __restrict__ row_ptr) {
    __shared__ int s[256];
    int i = blockIdx.x * 256 + threadIdx.x;
    int v = (i < N_NODES) ? deg[i] : 0;
    s[threadIdx.x] = v;
    __syncthreads();
    for (int off = 1; off < 256; off <<= 1) {
        int t = (threadIdx.x >= off) ? s[threadIdx.x - off] : 0;
        __syncthreads();
        s[threadIdx.x] += t;
        __syncthreads();
    }
    if (i < N_NODES) row_ptr[i + 1] = s[threadIdx.x] + bsum[blockIdx.x];
    if (i == 0) row_ptr[0] = 0;
}

// ---------- scatter edges into CSR buckets ----------
__global__ void k_scatter(const int* __restrict__ src, const int* __restrict__ dst,
                          const int* __restrict__ row_ptr, int* __restrict__ cnt,
                          int* __restrict__ col) {
    int e = blockIdx.x * blockDim.x + threadIdx.x;
    if (e < N_EDGES) {
        int d = dst[e];
        int pos = atomicAdd(&cnt[d], 1);
        col[row_ptr[d] + pos] = src[e];
    }
}

// ---------- SpMM hop (bf16 in/out, fp32 accumulate) ----------
// Wave = 4 groups x 16 lanes. Group g owns edge (base+g); lane l15 owns
// columns l15*8..l15*8+7 (16B dwordx4 slice). 2-deep unroll: 8 gathers in
// flight per wave. Cross-group reduce via shfl_xor(16,32).
__global__ __launch_bounds__(256) void k_spmm(const unsigned short* __restrict__ fin,
                                              const float* __restrict__ norm,
                                              const int* __restrict__ row_ptr,
                                              const int* __restrict__ col,
                                              unsigned short* __restrict__ fout) {
    int wave = threadIdx.x >> 6;
    int lane = threadIdx.x & 63;
    int grp = lane >> 4;
    int l15 = lane & 15;
    int v = blockIdx.x * 4 + wave;
    if (v >= N_NODES) return;
    int beg = row_ptr[v], end = row_ptr[v + 1];

    float a0[8], a1[8];
#pragma unroll
    for (int j = 0; j < 8; ++j) { a0[j] = 0.f; a1[j] = 0.f; }

    for (int base = beg; base < end; base += 8) {
        int e0 = base + grp;
        int e1 = base + 4 + grp;
        int ec0 = (e0 < end) ? e0 : end - 1;
        int ec1 = (e1 < end) ? e1 : end - 1;
        int u0 = col[ec0];
        int u1 = col[ec1];
        // issue both row-slice gathers before any use (8 gathers in flight/wave)
        uint4v r0 = *(const uint4v*)(fin + (size_t)u0 * 128 + l15 * 8);
        uint4v r1 = *(const uint4v*)(fin + (size_t)u1 * 128 + l15 * 8);
        float w0 = (e0 < end) ? norm[u0] : 0.f;
        float w1 = (e1 < end) ? norm[u1] : 0.f;
#pragma unroll
        for (int q = 0; q < 4; ++q) {
            a0[2 * q]     = fmaf(bflo(r0[q]), w0, a0[2 * q]);
            a0[2 * q + 1] = fmaf(bfhi(r0[q]), w0, a0[2 * q + 1]);
            a1[2 * q]     = fmaf(bflo(r1[q]), w1, a1[2 * q]);
            a1[2 * q + 1] = fmaf(bfhi(r1[q]), w1, a1[2 * q + 1]);
        }
    }

    // merge unroll pair, then reduce the 4 groups (same columns in all groups)
#pragma unroll
    for (int j = 0; j < 8; ++j) {
        float s = a0[j] + a1[j];
        s += __shfl_xor(s, 16, 64);
        s += __shfl_xor(s, 32, 64);
        a0[j] = s;
    }
    if (grp == 0) {
        float nv = norm[v];
        uint4v o;
#pragma unroll
        for (int q = 0; q < 4; ++q)
            o[q] = f2bf(a0[2 * q] * nv) | (f2bf(a0[2 * q + 1] * nv) << 16);
        *(uint4v*)(fout + (size_t)v * 128 + l15 * 8) = o;
    }
}

// ---------- bf16 MFMA GEMM: [A0|A1|A2] @ W(+bias), relu-store or fused pool ----------
// A0/A1/A2: [NPAD][128] bf16 row-major. Wt: [128 cols][384 k] bf16.
// Block = 256 thr = 4 waves; wave handles 32 rows x 128 cols (2x8 16x16 tiles).
template <bool RELU, bool POOL>
__global__ __launch_bounds__(256) void k_gemm_mfma(const unsigned short* __restrict__ A0,
                                                   const unsigned short* __restrict__ A1,
                                                   const unsigned short* __restrict__ A2,
                                                   const unsigned short* __restrict__ Wt,
                                                   const float* __restrict__ bias,
                                                   unsigned short* __restrict__ out,
                                                   const int* __restrict__ gid,
                                                   float* __restrict__ gsum) {
    __shared__ float red4[4][128];
    int tid = threadIdx.x;
    int lane = tid & 63;
    int wid = tid >> 6;
    int l15 = lane & 15;
    int lk = lane >> 4;                 // 0..3
    int n0 = blockIdx.x * 128;
    int rbase = n0 + wid * 32;

    float4v acc[2][8];
#pragma unroll
    for (int rt = 0; rt < 2; ++rt)
#pragma unroll
        for (int ct = 0; ct < 8; ++ct)
#pragma unroll
            for (int i = 0; i < 4; ++i) acc[rt][ct][i] = 0.f;

    const unsigned short* Aseg[3] = {A0, A1, A2};
#pragma unroll
    for (int ks = 0; ks < 12; ++ks) {
        const unsigned short* A = Aseg[ks >> 2];
        int kloc = (ks & 3) * 32 + lk * 8;
        short8v a0 = *(const short8v*)(A + (size_t)(rbase + l15) * 128 + kloc);
        short8v a1 = *(const short8v*)(A + (size_t)(rbase + 16 + l15) * 128 + kloc);
        const unsigned short* wp = Wt + (size_t)l15 * 384 + ks * 32 + lk * 8;
#pragma unroll
        for (int ct = 0; ct < 8; ++ct) {
            short8v b = *(const short8v*)(wp + (size_t)ct * 16 * 384);
            acc[0][ct] = __builtin_amdgcn_mfma_f32_16x16x32_bf16(a0, b, acc[0][ct], 0, 0, 0);
            acc[1][ct] = __builtin_amdgcn_mfma_f32_16x16x32_bf16(a1, b, acc[1][ct], 0, 0, 0);
        }
    }

    if (!POOL) {
        // epilogue: + bias, relu, bf16 store. C/D: col=lane&15, row=(lane>>4)*4+reg
        float bj[8];
#pragma unroll
        for (int ct = 0; ct < 8; ++ct) bj[ct] = bias[ct * 16 + l15];
#pragma unroll
        for (int rt = 0; rt < 2; ++rt)
#pragma unroll
            for (int i = 0; i < 4; ++i) {
                int row = rbase + rt * 16 + lk * 4 + i;
                if (row < N_NODES) {
#pragma unroll
                    for (int ct = 0; ct < 8; ++ct) {
                        float v = acc[rt][ct][i] + bj[ct];
                        if (RELU) v = fmaxf(v, 0.f);
                        out[(size_t)row * 128 + ct * 16 + l15] = (unsigned short)f2bf(v);
                    }
                }
            }
    } else {
        // fused mean-pool numerator (bias deferred to k_final)
        int gr[2][4];
#pragma unroll
        for (int rt = 0; rt < 2; ++rt)
#pragma unroll
            for (int i = 0; i < 4; ++i) {
                int row = rbase + rt * 16 + lk * 4 + i;
                gr[rt][i] = (row < N_NODES) ? gid[row] : -1;
            }
        int lastrow = n0 + 127;
        if (lastrow >= N_NODES) lastrow = N_NODES - 1;
        int gfirst = gid[n0];
        int glast = gid[lastrow];
        for (int g = gfirst; g <= glast; ++g) {
            float p[8];
#pragma unroll
            for (int ct = 0; ct < 8; ++ct) {
                float s = 0.f;
#pragma unroll
                for (int rt = 0; rt < 2; ++rt)
#pragma unroll
                    for (int i = 0; i < 4; ++i)
                        if (gr[rt][i] == g) s += acc[rt][ct][i];
                p[ct] = s;
            }
            // reduce across the 4 k-groups (lanes ^16, ^32 hold same col)
#pragma unroll
            for (int ct = 0; ct < 8; ++ct) {
                p[ct] += __shfl_xor(p[ct], 16, 64);
                p[ct] += __shfl_xor(p[ct], 32, 64);
            }
            if (lane < 16) {
#pragma unroll
                for (int ct = 0; ct < 8; ++ct) red4[wid][ct * 16 + lane] = p[ct];
            }
            __syncthreads();
            if (tid < 128) {
                float s = red4[0][tid] + red4[1][tid] + red4[2][tid] + red4[3][tid];
                atomicAdd(&gsum[g * 128 + tid], s);
            }
            __syncthreads();
        }
    }
}

// ---------- final: counts from run-starts; combined = gsum/cnt + b2 ; out = @Wc + bc ----------
__global__ void k_final(const float* __restrict__ gsum, const int* __restrict__ gstart,
                        const float* __restrict__ b2, const float* __restrict__ perm,
                        const float* __restrict__ Wc, const float* __restrict__ bc,
                        float* __restrict__ out) {
    int t = threadIdx.x;
    if (t >= B_GRAPHS * NCLS) return;
    int b = t / NCLS, c = t % NCLS;
    int s = gstart[b];
    float cf = 1.f;
    bool nonempty = (s >= 0);
    if (nonempty) {
        int nxt = N_NODES;
        for (int j = b + 1; j < B_GRAPHS; ++j) {
            int sj = gstart[j];
            if (sj >= 0) { nxt = sj; break; }
        }
        int cnt = nxt - s;
        cf = (cnt < 1) ? 1.f : (float)cnt;
    }
    float acc = bc[c];
    for (int d = 0; d < DH; ++d) {
        float hg = gsum[b * 128 + d] / cf + (nonempty ? b2[d] : 0.f);
        acc += hg * Wc[d * NCLS + c];
    }
    for (int p = 0; p < PFEAT; ++p) acc += perm[b * PFEAT + p] * Wc[(DH + p) * NCLS + c];
    out[t] = acc;
}

extern "C" void kernel_launch(void* const* d_in, const int* in_sizes, int n_in,
                              void* d_out, int out_size, void* d_ws, size_t ws_size,
                              hipStream_t stream) {
    const float* h    = (const float*)d_in[0];
    const int*   src  = (const int*)d_in[1];
    const int*   dst  = (const int*)d_in[2];
    const int*   gid  = (const int*)d_in[3];
    const float* perm = (const float*)d_in[4];
    const float* W1   = (const float*)d_in[5];
    const float* b1   = (const float*)d_in[6];
    const float* W2   = (const float*)d_in[7];
    const float* b2   = (const float*)d_in[8];
    const float* Wc   = (const float*)d_in[9];
    const float* bc   = (const float*)d_in[10];
    float* out = (float*)d_out;

    char* ws = (char*)d_ws;
    size_t off = 0;
    auto alloc = [&](size_t bytes) {
        void* p = ws + off;
        off = (off + bytes + 255) & ~(size_t)255;
        return p;
    };
    int*   deg     = (int*)alloc(N_NODES * 4);
    int*   cnt     = (int*)alloc(N_NODES * 4);
    int*   row_ptr = (int*)alloc((N_NODES + 1) * 4);
    int*   col     = (int*)alloc(N_EDGES * 4);
    int*   bsum    = (int*)alloc(SCAN_BLOCKS * 4);
    float* norm    = (float*)alloc(N_NODES * 4);
    unsigned short* h_bf = (unsigned short*)alloc((size_t)NPAD * 128 * 2);
    unsigned short* f1   = (unsigned short*)alloc((size_t)NPAD * 128 * 2);
    unsigned short* f2   = (unsigned short*)alloc((size_t)NPAD * 128 * 2);
    unsigned short* x2   = (unsigned short*)alloc((size_t)NPAD * 128 * 2);
    unsigned short* Wt1  = (unsigned short*)alloc(384 * 128 * 2);
    unsigned short* Wt2  = (unsigned short*)alloc(384 * 128 * 2);
    float* gsum    = (float*)alloc(B_GRAPHS * 128 * 4);
    int*   gstart  = (int*)alloc(B_GRAPHS * 4);

    hipMemsetAsync(deg, 0, N_NODES * 4, stream);
    hipMemsetAsync(cnt, 0, N_NODES * 4, stream);
    hipMemsetAsync(gsum, 0, B_GRAPHS * 128 * 4, stream);
    hipMemsetAsync(gstart, 0xFF, B_GRAPHS * 4, stream);  // -1 sentinel

    // dtype prep
    k_cvt<<<(N_NODES * 128 / 4 + 255) / 256, 256, 0, stream>>>(h, h_bf, N_NODES * 128 / 4);
    k_cvt_w<<<(384 * 128 + 255) / 256, 256, 0, stream>>>(W1, Wt1);
    k_cvt_w<<<(384 * 128 + 255) / 256, 256, 0, stream>>>(W2, Wt2);

    // CSR build
    k_deg<<<(N_EDGES + 255) / 256, 256, 0, stream>>>(dst, deg);
    k_norm<<<(N_NODES + 255) / 256, 256, 0, stream>>>(deg, norm);
    k_bound<<<(N_NODES + 255) / 256, 256, 0, stream>>>(gid, gstart);
    k_bsum<<<SCAN_BLOCKS, 256, 0, stream>>>(deg, bsum);
    k_bscan<<<1, 256, 0, stream>>>(bsum);
    k_scan2<<<SCAN_BLOCKS, 256, 0, stream>>>(deg, bsum, row_ptr);
    k_scatter<<<(N_EDGES + 255) / 256, 256, 0, stream>>>(src, dst, row_ptr, cnt, col);

    int spmm_grid = (N_NODES + 3) / 4;
    int gemm_grid = (N_NODES + 127) / 128;

    // Layer 1: feats = [h, f1, f2] -> x2 (relu, bf16)
    k_spmm<<<spmm_grid, 256, 0, stream>>>(h_bf, norm, row_ptr, col, f1);
    k_spmm<<<spmm_grid, 256, 0, stream>>>(f1, norm, row_ptr, col, f2);
    k_gemm_mfma<true, false><<<gemm_grid, 256, 0, stream>>>(h_bf, f1, f2, Wt1, b1, x2, gid, gsum);

    // Layer 2: feats = [x2, f1, f2] -> fused mean-pool numerator
    k_spmm<<<spmm_grid, 256, 0, stream>>>(x2, norm, row_ptr, col, f1);
    k_spmm<<<spmm_grid, 256, 0, stream>>>(f1, norm, row_ptr, col, f2);
    k_gemm_mfma<false, true><<<gemm_grid, 256, 0, stream>>>(x2, f1, f2, Wt2, nullptr, nullptr, gid, gsum);

    // Readout
    k_final<<<1, 128, 0, stream>>>(gsum, gstart, b2, perm, Wc, bc, out);
}

// Round 6
// 269.924 us; speedup vs baseline: 2.9513x; 1.0318x over previous
//
#include <hip/hip_runtime.h>

#define N_NODES 50000
#define N_EDGES 600000
#define B_GRAPHS 64
#define DH 128
#define PFEAT 32
#define NCLS 2
#define SCAN_BLOCKS ((N_NODES + 255) / 256)   // 196
#define NPAD (N_NODES + 128)                  // row padding for OOB-safe MFMA loads
#define NCVT4 (N_NODES * 128 / 4)             // 1,600,000
#define WELEMS (384 * 128)                    // 49,152

typedef __attribute__((ext_vector_type(8))) short short8v;
typedef __attribute__((ext_vector_type(4))) float float4v;
typedef __attribute__((ext_vector_type(4))) unsigned int uint4v;

__device__ __forceinline__ unsigned int f2bf(float f) {
    unsigned int u = __float_as_uint(f);
    return (u + 0x7FFFu + ((u >> 16) & 1u)) >> 16;   // RNE
}
__device__ __forceinline__ float bflo(unsigned int p) { return __uint_as_float(p << 16); }
__device__ __forceinline__ float bfhi(unsigned int p) { return __uint_as_float(p & 0xFFFF0000u); }

// ---------- fused init: zero scratch + h->bf16 + W1/W2 transpose-convert ----------
__global__ void k_init(const float* __restrict__ h, unsigned short* __restrict__ h_bf,
                       const float* __restrict__ W1, const float* __restrict__ W2,
                       unsigned short* __restrict__ Wt1, unsigned short* __restrict__ Wt2,
                       int* __restrict__ deg, int* __restrict__ cnt,
                       float* __restrict__ gsum, int* __restrict__ gstart) {
    int t = blockIdx.x * 256 + threadIdx.x;
    if (t < NCVT4) {
        float4 v = ((const float4*)h)[t];
        unsigned int lo = f2bf(v.x) | (f2bf(v.y) << 16);
        unsigned int hi = f2bf(v.z) | (f2bf(v.w) << 16);
        uint2 r; r.x = lo; r.y = hi;
        ((uint2*)h_bf)[t] = r;
    }
    if (t < 2 * WELEMS) {
        bool second = (t >= WELEMS);
        int idx = second ? t - WELEMS : t;
        const float* W = second ? W2 : W1;
        unsigned short* Wt = second ? Wt2 : Wt1;
        int k = idx >> 7, c = idx & 127;
        Wt[c * 384 + k] = (unsigned short)f2bf(W[idx]);
    }
    if (t < N_NODES) { deg[t] = 0; cnt[t] = 0; }
    if (t < B_GRAPHS * DH) gsum[t] = 0.f;
    if (t < B_GRAPHS) gstart[t] = -1;
}

// ---------- fused: degree atomics + graph run-starts ----------
__global__ void k_deg_bound(const int* __restrict__ dst, const int* __restrict__ gid,
                            int* __restrict__ deg, int* __restrict__ gstart) {
    int t = blockIdx.x * 256 + threadIdx.x;
    if (t < N_EDGES) atomicAdd(&deg[dst[t]], 1);
    int n = t - N_EDGES;
    if (n >= 0 && n < N_NODES) {
        int g = gid[n];
        if (n == 0 || gid[n - 1] != g) gstart[g] = n;
    }
}

// ---------- fused: norm + per-block degree sums ----------
__global__ void k_norm_bsum(const int* __restrict__ deg, float* __restrict__ norm,
                            int* __restrict__ bsum) {
    __shared__ int s[256];
    int i = blockIdx.x * 256 + threadIdx.x;
    int d = (i < N_NODES) ? deg[i] : 0;
    if (i < N_NODES) norm[i] = rsqrtf((float)(d < 1 ? 1 : d));
    s[threadIdx.x] = d;
    __syncthreads();
    for (int off = 128; off > 0; off >>= 1) {
        if (threadIdx.x < off) s[threadIdx.x] += s[threadIdx.x + off];
        __syncthreads();
    }
    if (threadIdx.x == 0) bsum[blockIdx.x] = s[0];
}

// ---------- single-block exclusive scan of block sums ----------
__global__ void k_bscan(int* __restrict__ bsum) {
    __shared__ int s[256];
    int v = (threadIdx.x < SCAN_BLOCKS) ? bsum[threadIdx.x] : 0;
    s[threadIdx.x] = v;
    __syncthreads();
    for (int off = 1; off < 256; off <<= 1) {
        int t = (threadIdx.x >= off) ? s[threadIdx.x - off] : 0;
        __syncthreads();
        s[threadIdx.x] += t;
        __syncthreads();
    }
    if (threadIdx.x < SCAN_BLOCKS) bsum[threadIdx.x] = s[threadIdx.x] - v;
}

// ---------- per-block inclusive scan + offset -> row_ptr ----------
__global__ void k_scan2(const int* __restrict__ deg, const int* __restrict__ bsum,
                        int* __restrict__ row_ptr) {
    __shared__ int s[256];
    int i = blockIdx.x * 256 + threadIdx.x;
    int v = (i < N_NODES) ? deg[i] : 0;
    s[threadIdx.x] = v;
    __syncthreads();
    for (int off = 1; off < 256; off <<= 1) {
        int t = (threadIdx.x >= off) ? s[threadIdx.x - off] : 0;
        __syncthreads();
        s[threadIdx.x] += t;
        __syncthreads();
    }
    if (i < N_NODES) row_ptr[i + 1] = s[threadIdx.x] + bsum[blockIdx.x];
    if (i == 0) row_ptr[0] = 0;
}

// ---------- scatter edges into CSR buckets ----------
__global__ void k_scatter(const int* __restrict__ src, const int* __restrict__ dst,
                          const int* __restrict__ row_ptr, int* __restrict__ cnt,
                          int* __restrict__ col) {
    int e = blockIdx.x * blockDim.x + threadIdx.x;
    if (e < N_EDGES) {
        int d = dst[e];
        int pos = atomicAdd(&cnt[d], 1);
        col[row_ptr[d] + pos] = src[e];
    }
}

// ---------- SpMM hop (bf16 in/out, fp32 accumulate) ----------
// Wave = 4 groups x 16 lanes; 4-deep edge pipeline: 16 edge-slots per
// iteration, up to 16 row-slice gathers in flight per wave. Lane l15 owns
// columns l15*8..+7 (16B dwordx4). Cross-group reduce via shfl_xor(16,32).
__global__ __launch_bounds__(256) void k_spmm(const unsigned short* __restrict__ fin,
                                              const float* __restrict__ norm,
                                              const int* __restrict__ row_ptr,
                                              const int* __restrict__ col,
                                              unsigned short* __restrict__ fout) {
    int wave = threadIdx.x >> 6;
    int lane = threadIdx.x & 63;
    int grp = lane >> 4;
    int l15 = lane & 15;
    int v = blockIdx.x * 4 + wave;
    if (v >= N_NODES) return;
    int beg = row_ptr[v], end = row_ptr[v + 1];

    float a0[8], a1[8], a2[8], a3[8];
#pragma unroll
    for (int j = 0; j < 8; ++j) { a0[j] = 0.f; a1[j] = 0.f; a2[j] = 0.f; a3[j] = 0.f; }

    for (int base = beg; base < end; base += 16) {
        int e0 = base + grp;
        int e1 = e0 + 4, e2 = e0 + 8, e3 = e0 + 12;
        int last = end - 1;
        int c0 = (e0 < end) ? e0 : last;
        int c1 = (e1 < end) ? e1 : last;
        int c2 = (e2 < end) ? e2 : last;
        int c3 = (e3 < end) ? e3 : last;
        int u0 = col[c0], u1 = col[c1], u2 = col[c2], u3 = col[c3];
        uint4v r0 = *(const uint4v*)(fin + (size_t)u0 * 128 + l15 * 8);
        uint4v r1 = *(const uint4v*)(fin + (size_t)u1 * 128 + l15 * 8);
        uint4v r2 = *(const uint4v*)(fin + (size_t)u2 * 128 + l15 * 8);
        uint4v r3 = *(const uint4v*)(fin + (size_t)u3 * 128 + l15 * 8);
        float w0 = (e0 < end) ? norm[u0] : 0.f;
        float w1 = (e1 < end) ? norm[u1] : 0.f;
        float w2 = (e2 < end) ? norm[u2] : 0.f;
        float w3 = (e3 < end) ? norm[u3] : 0.f;
#pragma unroll
        for (int q = 0; q < 4; ++q) {
            a0[2 * q]     = fmaf(bflo(r0[q]), w0, a0[2 * q]);
            a0[2 * q + 1] = fmaf(bfhi(r0[q]), w0, a0[2 * q + 1]);
            a1[2 * q]     = fmaf(bflo(r1[q]), w1, a1[2 * q]);
            a1[2 * q + 1] = fmaf(bfhi(r1[q]), w1, a1[2 * q + 1]);
            a2[2 * q]     = fmaf(bflo(r2[q]), w2, a2[2 * q]);
            a2[2 * q + 1] = fmaf(bfhi(r2[q]), w2, a2[2 * q + 1]);
            a3[2 * q]     = fmaf(bflo(r3[q]), w3, a3[2 * q]);
            a3[2 * q + 1] = fmaf(bfhi(r3[q]), w3, a3[2 * q + 1]);
        }
    }

    // merge unroll slots, then reduce the 4 groups (same columns in all groups)
#pragma unroll
    for (int j = 0; j < 8; ++j) {
        float s = (a0[j] + a1[j]) + (a2[j] + a3[j]);
        s += __shfl_xor(s, 16, 64);
        s += __shfl_xor(s, 32, 64);
        a0[j] = s;
    }
    if (grp == 0) {
        float nv = norm[v];
        uint4v o;
#pragma unroll
        for (int q = 0; q < 4; ++q)
            o[q] = f2bf(a0[2 * q] * nv) | (f2bf(a0[2 * q + 1] * nv) << 16);
        *(uint4v*)(fout + (size_t)v * 128 + l15 * 8) = o;
    }
}

// ---------- bf16 MFMA GEMM: [A0|A1|A2] @ W(+bias), relu-store or fused pool ----------
// A0/A1/A2: [NPAD][128] bf16 row-major. Wt: [128 cols][384 k] bf16.
// Block = 256 thr = 4 waves; wave handles 32 rows x 128 cols (2x8 16x16 tiles).
template <bool RELU, bool POOL>
__global__ __launch_bounds__(256) void k_gemm_mfma(const unsigned short* __restrict__ A0,
                                                   const unsigned short* __restrict__ A1,
                                                   const unsigned short* __restrict__ A2,
                                                   const unsigned short* __restrict__ Wt,
                                                   const float* __restrict__ bias,
                                                   unsigned short* __restrict__ out,
                                                   const int* __restrict__ gid,
                                                   float* __restrict__ gsum) {
    __shared__ float red4[4][128];
    int tid = threadIdx.x;
    int lane = tid & 63;
    int wid = tid >> 6;
    int l15 = lane & 15;
    int lk = lane >> 4;                 // 0..3
    int n0 = blockIdx.x * 128;
    int rbase = n0 + wid * 32;

    float4v acc[2][8];
#pragma unroll
    for (int rt = 0; rt < 2; ++rt)
#pragma unroll
        for (int ct = 0; ct < 8; ++ct)
#pragma unroll
            for (int i = 0; i < 4; ++i) acc[rt][ct][i] = 0.f;

    const unsigned short* Aseg[3] = {A0, A1, A2};
#pragma unroll
    for (int ks = 0; ks < 12; ++ks) {
        const unsigned short* A = Aseg[ks >> 2];
        int kloc = (ks & 3) * 32 + lk * 8;
        short8v a0 = *(const short8v*)(A + (size_t)(rbase + l15) * 128 + kloc);
        short8v a1 = *(const short8v*)(A + (size_t)(rbase + 16 + l15) * 128 + kloc);
        const unsigned short* wp = Wt + (size_t)l15 * 384 + ks * 32 + lk * 8;
#pragma unroll
        for (int ct = 0; ct < 8; ++ct) {
            short8v b = *(const short8v*)(wp + (size_t)ct * 16 * 384);
            acc[0][ct] = __builtin_amdgcn_mfma_f32_16x16x32_bf16(a0, b, acc[0][ct], 0, 0, 0);
            acc[1][ct] = __builtin_amdgcn_mfma_f32_16x16x32_bf16(a1, b, acc[1][ct], 0, 0, 0);
        }
    }

    if (!POOL) {
        // epilogue: + bias, relu, bf16 store. C/D: col=lane&15, row=(lane>>4)*4+reg
        float bj[8];
#pragma unroll
        for (int ct = 0; ct < 8; ++ct) bj[ct] = bias[ct * 16 + l15];
#pragma unroll
        for (int rt = 0; rt < 2; ++rt)
#pragma unroll
            for (int i = 0; i < 4; ++i) {
                int row = rbase + rt * 16 + lk * 4 + i;
                if (row < N_NODES) {
#pragma unroll
                    for (int ct = 0; ct < 8; ++ct) {
                        float v = acc[rt][ct][i] + bj[ct];
                        if (RELU) v = fmaxf(v, 0.f);
                        out[(size_t)row * 128 + ct * 16 + l15] = (unsigned short)f2bf(v);
                    }
                }
            }
    } else {
        // fused mean-pool numerator (bias deferred to k_final)
        int gr[2][4];
#pragma unroll
        for (int rt = 0; rt < 2; ++rt)
#pragma unroll
            for (int i = 0; i < 4; ++i) {
                int row = rbase + rt * 16 + lk * 4 + i;
                gr[rt][i] = (row < N_NODES) ? gid[row] : -1;
            }
        int lastrow = n0 + 127;
        if (lastrow >= N_NODES) lastrow = N_NODES - 1;
        int gfirst = gid[n0];
        int glast = gid[lastrow];
        for (int g = gfirst; g <= glast; ++g) {
            float p[8];
#pragma unroll
            for (int ct = 0; ct < 8; ++ct) {
                float s = 0.f;
#pragma unroll
                for (int rt = 0; rt < 2; ++rt)
#pragma unroll
                    for (int i = 0; i < 4; ++i)
                        if (gr[rt][i] == g) s += acc[rt][ct][i];
                p[ct] = s;
            }
            // reduce across the 4 k-groups (lanes ^16, ^32 hold same col)
#pragma unroll
            for (int ct = 0; ct < 8; ++ct) {
                p[ct] += __shfl_xor(p[ct], 16, 64);
                p[ct] += __shfl_xor(p[ct], 32, 64);
            }
            if (lane < 16) {
#pragma unroll
                for (int ct = 0; ct < 8; ++ct) red4[wid][ct * 16 + lane] = p[ct];
            }
            __syncthreads();
            if (tid < 128) {
                float s = red4[0][tid] + red4[1][tid] + red4[2][tid] + red4[3][tid];
                atomicAdd(&gsum[g * 128 + tid], s);
            }
            __syncthreads();
        }
    }
}

// ---------- final: counts from run-starts; combined = gsum/cnt + b2 ; out = @Wc + bc ----------
__global__ void k_final(const float* __restrict__ gsum, const int* __restrict__ gstart,
                        const float* __restrict__ b2, const float* __restrict__ perm,
                        const float* __restrict__ Wc, const float* __restrict__ bc,
                        float* __restrict__ out) {
    int t = threadIdx.x;
    if (t >= B_GRAPHS * NCLS) return;
    int b = t / NCLS, c = t % NCLS;
    int s = gstart[b];
    float cf = 1.f;
    bool nonempty = (s >= 0);
    if (nonempty) {
        int nxt = N_NODES;
        for (int j = b + 1; j < B_GRAPHS; ++j) {
            int sj = gstart[j];
            if (sj >= 0) { nxt = sj; break; }
        }
        int cnt = nxt - s;
        cf = (cnt < 1) ? 1.f : (float)cnt;
    }
    float acc = bc[c];
    for (int d = 0; d < DH; ++d) {
        float hg = gsum[b * 128 + d] / cf + (nonempty ? b2[d] : 0.f);
        acc += hg * Wc[d * NCLS + c];
    }
    for (int p = 0; p < PFEAT; ++p) acc += perm[b * PFEAT + p] * Wc[(DH + p) * NCLS + c];
    out[t] = acc;
}

extern "C" void kernel_launch(void* const* d_in, const int* in_sizes, int n_in,
                              void* d_out, int out_size, void* d_ws, size_t ws_size,
                              hipStream_t stream) {
    const float* h    = (const float*)d_in[0];
    const int*   src  = (const int*)d_in[1];
    const int*   dst  = (const int*)d_in[2];
    const int*   gid  = (const int*)d_in[3];
    const float* perm = (const float*)d_in[4];
    const float* W1   = (const float*)d_in[5];
    const float* b1   = (const float*)d_in[6];
    const float* W2   = (const float*)d_in[7];
    const float* b2   = (const float*)d_in[8];
    const float* Wc   = (const float*)d_in[9];
    const float* bc   = (const float*)d_in[10];
    float* out = (float*)d_out;

    char* ws = (char*)d_ws;
    size_t off = 0;
    auto alloc = [&](size_t bytes) {
        void* p = ws + off;
        off = (off + bytes + 255) & ~(size_t)255;
        return p;
    };
    int*   deg     = (int*)alloc(N_NODES * 4);
    int*   cnt     = (int*)alloc(N_NODES * 4);
    int*   row_ptr = (int*)alloc((N_NODES + 1) * 4);
    int*   col     = (int*)alloc(N_EDGES * 4);
    int*   bsum    = (int*)alloc(SCAN_BLOCKS * 4);
    float* norm    = (float*)alloc(N_NODES * 4);
    unsigned short* h_bf = (unsigned short*)alloc((size_t)NPAD * 128 * 2);
    unsigned short* f1   = (unsigned short*)alloc((size_t)NPAD * 128 * 2);
    unsigned short* f2   = (unsigned short*)alloc((size_t)NPAD * 128 * 2);
    unsigned short* x2   = (unsigned short*)alloc((size_t)NPAD * 128 * 2);
    unsigned short* Wt1  = (unsigned short*)alloc(384 * 128 * 2);
    unsigned short* Wt2  = (unsigned short*)alloc(384 * 128 * 2);
    float* gsum    = (float*)alloc(B_GRAPHS * 128 * 4);
    int*   gstart  = (int*)alloc(B_GRAPHS * 4);

    // one fused init dispatch: zeroing + h->bf16 + W transposes
    k_init<<<(NCVT4 + 255) / 256, 256, 0, stream>>>(h, h_bf, W1, W2, Wt1, Wt2,
                                                    deg, cnt, gsum, gstart);
    // CSR build (fused)
    k_deg_bound<<<(N_EDGES + N_NODES + 255) / 256, 256, 0, stream>>>(dst, gid, deg, gstart);
    k_norm_bsum<<<SCAN_BLOCKS, 256, 0, stream>>>(deg, norm, bsum);
    k_bscan<<<1, 256, 0, stream>>>(bsum);
    k_scan2<<<SCAN_BLOCKS, 256, 0, stream>>>(deg, bsum, row_ptr);
    k_scatter<<<(N_EDGES + 255) / 256, 256, 0, stream>>>(src, dst, row_ptr, cnt, col);

    int spmm_grid = (N_NODES + 3) / 4;
    int gemm_grid = (N_NODES + 127) / 128;

    // Layer 1: feats = [h, f1, f2] -> x2 (relu, bf16)
    k_spmm<<<spmm_grid, 256, 0, stream>>>(h_bf, norm, row_ptr, col, f1);
    k_spmm<<<spmm_grid, 256, 0, stream>>>(f1, norm, row_ptr, col, f2);
    k_gemm_mfma<true, false><<<gemm_grid, 256, 0, stream>>>(h_bf, f1, f2, Wt1, b1, x2, gid, gsum);

    // Layer 2: feats = [x2, f1, f2] -> fused mean-pool numerator
    k_spmm<<<spmm_grid, 256, 0, stream>>>(x2, norm, row_ptr, col, f1);
    k_spmm<<<spmm_grid, 256, 0, stream>>>(f1, norm, row_ptr, col, f2);
    k_gemm_mfma<false, true><<<gemm_grid, 256, 0, stream>>>(x2, f1, f2, Wt2, nullptr, nullptr, gid, gsum);

    // Readout
    k_final<<<1, 128, 0, stream>>>(gsum, gstart, b2, perm, Wc, bc, out);
}

// Round 7
// 248.314 us; speedup vs baseline: 3.2081x; 1.0870x over previous
//
#include <hip/hip_runtime.h>

#define N_NODES 50000
#define N_EDGES 600000
#define B_GRAPHS 64
#define DH 128
#define PFEAT 32
#define NCLS 2
#define SCAN_BLOCKS ((N_NODES + 255) / 256)   // 196
#define NPAD (N_NODES + 128)                  // row padding for OOB-safe MFMA loads
#define NCVT4 (N_NODES * 128 / 4)             // 1,600,000
#define WELEMS (384 * 128)                    // 49,152

typedef __attribute__((ext_vector_type(8))) short short8v;
typedef __attribute__((ext_vector_type(4))) float float4v;
typedef __attribute__((ext_vector_type(4))) unsigned int uint4v;

__device__ __forceinline__ unsigned int f2bf(float f) {
    unsigned int u = __float_as_uint(f);
    return (u + 0x7FFFu + ((u >> 16) & 1u)) >> 16;   // RNE
}
__device__ __forceinline__ float bflo(unsigned int p) { return __uint_as_float(p << 16); }
__device__ __forceinline__ float bfhi(unsigned int p) { return __uint_as_float(p & 0xFFFF0000u); }

// ---------- fused init: zero scratch + h->bf16 + W1/W2 transpose-convert ----------
__global__ void k_init(const float* __restrict__ h, unsigned short* __restrict__ h_bf,
                       const float* __restrict__ W1, const float* __restrict__ W2,
                       unsigned short* __restrict__ Wt1, unsigned short* __restrict__ Wt2,
                       int* __restrict__ deg, float* __restrict__ gsum,
                       int* __restrict__ gstart) {
    int t = blockIdx.x * 256 + threadIdx.x;
    if (t < NCVT4) {
        float4 v = ((const float4*)h)[t];
        unsigned int lo = f2bf(v.x) | (f2bf(v.y) << 16);
        unsigned int hi = f2bf(v.z) | (f2bf(v.w) << 16);
        uint2 r; r.x = lo; r.y = hi;
        ((uint2*)h_bf)[t] = r;
    }
    if (t < 2 * WELEMS) {
        bool second = (t >= WELEMS);
        int idx = second ? t - WELEMS : t;
        const float* W = second ? W2 : W1;
        unsigned short* Wt = second ? Wt2 : Wt1;
        int k = idx >> 7, c = idx & 127;
        Wt[c * 384 + k] = (unsigned short)f2bf(W[idx]);
    }
    if (t < N_NODES) deg[t] = 0;
    if (t < B_GRAPHS * DH) gsum[t] = 0.f;
    if (t < B_GRAPHS) gstart[t] = -1;
}

// ---------- fused: degree atomics (saving bucket positions) + graph run-starts ----------
__global__ void k_deg_bound(const int* __restrict__ dst, const int* __restrict__ gid,
                            int* __restrict__ deg, int* __restrict__ epos,
                            int* __restrict__ gstart) {
    int t = blockIdx.x * 256 + threadIdx.x;
    if (t < N_EDGES) {
        int pos = atomicAdd(&deg[dst[t]], 1);
        epos[t] = pos;
    }
    int n = t - N_EDGES;
    if (n >= 0 && n < N_NODES) {
        int g = gid[n];
        if (n == 0 || gid[n - 1] != g) gstart[g] = n;
    }
}

// ---------- fused: norm + per-block degree sums ----------
__global__ void k_norm_bsum(const int* __restrict__ deg, float* __restrict__ norm,
                            int* __restrict__ bsum) {
    __shared__ int s[256];
    int i = blockIdx.x * 256 + threadIdx.x;
    int d = (i < N_NODES) ? deg[i] : 0;
    if (i < N_NODES) norm[i] = rsqrtf((float)(d < 1 ? 1 : d));
    s[threadIdx.x] = d;
    __syncthreads();
    for (int off = 128; off > 0; off >>= 1) {
        if (threadIdx.x < off) s[threadIdx.x] += s[threadIdx.x + off];
        __syncthreads();
    }
    if (threadIdx.x == 0) bsum[blockIdx.x] = s[0];
}

// ---------- scan:每 block redundantly scans 196 block-sums in LDS, then local scan ----------
__global__ void k_scan2(const int* __restrict__ deg, const int* __restrict__ bsum,
                        int* __restrict__ row_ptr) {
    __shared__ int sb[256];
    __shared__ int s[256];
    // redundant scan of the tiny block-sum array (inclusive)
    int bv = (threadIdx.x < SCAN_BLOCKS) ? bsum[threadIdx.x] : 0;
    sb[threadIdx.x] = bv;
    int i = blockIdx.x * 256 + threadIdx.x;
    int v = (i < N_NODES) ? deg[i] : 0;
    s[threadIdx.x] = v;
    __syncthreads();
    for (int off = 1; off < 256; off <<= 1) {
        int tb = (threadIdx.x >= off) ? sb[threadIdx.x - off] : 0;
        int t = (threadIdx.x >= off) ? s[threadIdx.x - off] : 0;
        __syncthreads();
        sb[threadIdx.x] += tb;
        s[threadIdx.x] += t;
        __syncthreads();
    }
    int block_off = (blockIdx.x == 0) ? 0 : sb[blockIdx.x - 1];
    if (i < N_NODES) row_ptr[i + 1] = s[threadIdx.x] + block_off;
    if (i == 0) row_ptr[0] = 0;
}

// ---------- scatter edges into CSR buckets (no atomics: positions precomputed) ----------
__global__ void k_scatter(const int* __restrict__ src, const int* __restrict__ dst,
                          const int* __restrict__ row_ptr, const int* __restrict__ epos,
                          int* __restrict__ col) {
    int e = blockIdx.x * blockDim.x + threadIdx.x;
    if (e < N_EDGES) {
        int d = dst[e];
        col[row_ptr[d] + epos[e]] = src[e];
    }
}

// ---------- SpMM hop (bf16 in/out, fp32 accumulate) ----------
// Wave = 4 groups x 16 lanes; 4-deep edge pipeline: 16 edge-slots per
// iteration, up to 16 row-slice gathers in flight per wave. Lane l15 owns
// columns l15*8..+7 (16B dwordx4). Cross-group reduce via shfl_xor(16,32).
__global__ __launch_bounds__(256) void k_spmm(const unsigned short* __restrict__ fin,
                                              const float* __restrict__ norm,
                                              const int* __restrict__ row_ptr,
                                              const int* __restrict__ col,
                                              unsigned short* __restrict__ fout) {
    int wave = threadIdx.x >> 6;
    int lane = threadIdx.x & 63;
    int grp = lane >> 4;
    int l15 = lane & 15;
    int v = blockIdx.x * 4 + wave;
    if (v >= N_NODES) return;
    int beg = row_ptr[v], end = row_ptr[v + 1];

    float a0[8], a1[8], a2[8], a3[8];
#pragma unroll
    for (int j = 0; j < 8; ++j) { a0[j] = 0.f; a1[j] = 0.f; a2[j] = 0.f; a3[j] = 0.f; }

    for (int base = beg; base < end; base += 16) {
        int e0 = base + grp;
        int e1 = e0 + 4, e2 = e0 + 8, e3 = e0 + 12;
        int last = end - 1;
        int c0 = (e0 < end) ? e0 : last;
        int c1 = (e1 < end) ? e1 : last;
        int c2 = (e2 < end) ? e2 : last;
        int c3 = (e3 < end) ? e3 : last;
        int u0 = col[c0], u1 = col[c1], u2 = col[c2], u3 = col[c3];
        uint4v r0 = *(const uint4v*)(fin + (size_t)u0 * 128 + l15 * 8);
        uint4v r1 = *(const uint4v*)(fin + (size_t)u1 * 128 + l15 * 8);
        uint4v r2 = *(const uint4v*)(fin + (size_t)u2 * 128 + l15 * 8);
        uint4v r3 = *(const uint4v*)(fin + (size_t)u3 * 128 + l15 * 8);
        float w0 = (e0 < end) ? norm[u0] : 0.f;
        float w1 = (e1 < end) ? norm[u1] : 0.f;
        float w2 = (e2 < end) ? norm[u2] : 0.f;
        float w3 = (e3 < end) ? norm[u3] : 0.f;
#pragma unroll
        for (int q = 0; q < 4; ++q) {
            a0[2 * q]     = fmaf(bflo(r0[q]), w0, a0[2 * q]);
            a0[2 * q + 1] = fmaf(bfhi(r0[q]), w0, a0[2 * q + 1]);
            a1[2 * q]     = fmaf(bflo(r1[q]), w1, a1[2 * q]);
            a1[2 * q + 1] = fmaf(bfhi(r1[q]), w1, a1[2 * q + 1]);
            a2[2 * q]     = fmaf(bflo(r2[q]), w2, a2[2 * q]);
            a2[2 * q + 1] = fmaf(bfhi(r2[q]), w2, a2[2 * q + 1]);
            a3[2 * q]     = fmaf(bflo(r3[q]), w3, a3[2 * q]);
            a3[2 * q + 1] = fmaf(bfhi(r3[q]), w3, a3[2 * q + 1]);
        }
    }

    // merge unroll slots, then reduce the 4 groups (same columns in all groups)
#pragma unroll
    for (int j = 0; j < 8; ++j) {
        float s = (a0[j] + a1[j]) + (a2[j] + a3[j]);
        s += __shfl_xor(s, 16, 64);
        s += __shfl_xor(s, 32, 64);
        a0[j] = s;
    }
    if (grp == 0) {
        float nv = norm[v];
        uint4v o;
#pragma unroll
        for (int q = 0; q < 4; ++q)
            o[q] = f2bf(a0[2 * q] * nv) | (f2bf(a0[2 * q + 1] * nv) << 16);
        *(uint4v*)(fout + (size_t)v * 128 + l15 * 8) = o;
    }
}

// ---------- bf16 MFMA GEMM: [A0|A1|A2] @ W(+bias), relu-store or fused pool ----------
// A0/A1/A2: [NPAD][128] bf16 row-major. Wt: [128 cols][384 k] bf16.
// Block = 256 thr = 4 waves; wave handles 32 rows x 128 cols (2x8 16x16 tiles).
template <bool RELU, bool POOL>
__global__ __launch_bounds__(256) void k_gemm_mfma(const unsigned short* __restrict__ A0,
                                                   const unsigned short* __restrict__ A1,
                                                   const unsigned short* __restrict__ A2,
                                                   const unsigned short* __restrict__ Wt,
                                                   const float* __restrict__ bias,
                                                   unsigned short* __restrict__ out,
                                                   const int* __restrict__ gid,
                                                   float* __restrict__ gsum) {
    __shared__ float red4[4][128];
    int tid = threadIdx.x;
    int lane = tid & 63;
    int wid = tid >> 6;
    int l15 = lane & 15;
    int lk = lane >> 4;                 // 0..3
    int n0 = blockIdx.x * 128;
    int rbase = n0 + wid * 32;

    float4v acc[2][8];
#pragma unroll
    for (int rt = 0; rt < 2; ++rt)
#pragma unroll
        for (int ct = 0; ct < 8; ++ct)
#pragma unroll
            for (int i = 0; i < 4; ++i) acc[rt][ct][i] = 0.f;

    const unsigned short* Aseg[3] = {A0, A1, A2};
#pragma unroll
    for (int ks = 0; ks < 12; ++ks) {
        const unsigned short* A = Aseg[ks >> 2];
        int kloc = (ks & 3) * 32 + lk * 8;
        short8v a0 = *(const short8v*)(A + (size_t)(rbase + l15) * 128 + kloc);
        short8v a1 = *(const short8v*)(A + (size_t)(rbase + 16 + l15) * 128 + kloc);
        const unsigned short* wp = Wt + (size_t)l15 * 384 + ks * 32 + lk * 8;
#pragma unroll
        for (int ct = 0; ct < 8; ++ct) {
            short8v b = *(const short8v*)(wp + (size_t)ct * 16 * 384);
            acc[0][ct] = __builtin_amdgcn_mfma_f32_16x16x32_bf16(a0, b, acc[0][ct], 0, 0, 0);
            acc[1][ct] = __builtin_amdgcn_mfma_f32_16x16x32_bf16(a1, b, acc[1][ct], 0, 0, 0);
        }
    }

    if (!POOL) {
        // epilogue: + bias, relu, bf16 store. C/D: col=lane&15, row=(lane>>4)*4+reg
        float bj[8];
#pragma unroll
        for (int ct = 0; ct < 8; ++ct) bj[ct] = bias[ct * 16 + l15];
#pragma unroll
        for (int rt = 0; rt < 2; ++rt)
#pragma unroll
            for (int i = 0; i < 4; ++i) {
                int row = rbase + rt * 16 + lk * 4 + i;
                if (row < N_NODES) {
#pragma unroll
                    for (int ct = 0; ct < 8; ++ct) {
                        float v = acc[rt][ct][i] + bj[ct];
                        if (RELU) v = fmaxf(v, 0.f);
                        out[(size_t)row * 128 + ct * 16 + l15] = (unsigned short)f2bf(v);
                    }
                }
            }
    } else {
        // fused mean-pool numerator (bias deferred to k_final)
        int gr[2][4];
#pragma unroll
        for (int rt = 0; rt < 2; ++rt)
#pragma unroll
            for (int i = 0; i < 4; ++i) {
                int row = rbase + rt * 16 + lk * 4 + i;
                gr[rt][i] = (row < N_NODES) ? gid[row] : -1;
            }
        int lastrow = n0 + 127;
        if (lastrow >= N_NODES) lastrow = N_NODES - 1;
        int gfirst = gid[n0];
        int glast = gid[lastrow];
        for (int g = gfirst; g <= glast; ++g) {
            float p[8];
#pragma unroll
            for (int ct = 0; ct < 8; ++ct) {
                float s = 0.f;
#pragma unroll
                for (int rt = 0; rt < 2; ++rt)
#pragma unroll
                    for (int i = 0; i < 4; ++i)
                        if (gr[rt][i] == g) s += acc[rt][ct][i];
                p[ct] = s;
            }
            // reduce across the 4 k-groups (lanes ^16, ^32 hold same col)
#pragma unroll
            for (int ct = 0; ct < 8; ++ct) {
                p[ct] += __shfl_xor(p[ct], 16, 64);
                p[ct] += __shfl_xor(p[ct], 32, 64);
            }
            if (lane < 16) {
#pragma unroll
                for (int ct = 0; ct < 8; ++ct) red4[wid][ct * 16 + lane] = p[ct];
            }
            __syncthreads();
            if (tid < 128) {
                float s = red4[0][tid] + red4[1][tid] + red4[2][tid] + red4[3][tid];
                atomicAdd(&gsum[g * 128 + tid], s);
            }
            __syncthreads();
        }
    }
}

// ---------- final: counts from run-starts; combined = gsum/cnt + b2 ; out = @Wc + bc ----------
__global__ void k_final(const float* __restrict__ gsum, const int* __restrict__ gstart,
                        const float* __restrict__ b2, const float* __restrict__ perm,
                        const float* __restrict__ Wc, const float* __restrict__ bc,
                        float* __restrict__ out) {
    int t = threadIdx.x;
    if (t >= B_GRAPHS * NCLS) return;
    int b = t / NCLS, c = t % NCLS;
    int s = gstart[b];
    float cf = 1.f;
    bool nonempty = (s >= 0);
    if (nonempty) {
        int nxt = N_NODES;
        for (int j = b + 1; j < B_GRAPHS; ++j) {
            int sj = gstart[j];
            if (sj >= 0) { nxt = sj; break; }
        }
        int cnt = nxt - s;
        cf = (cnt < 1) ? 1.f : (float)cnt;
    }
    float acc = bc[c];
    for (int d = 0; d < DH; ++d) {
        float hg = gsum[b * 128 + d] / cf + (nonempty ? b2[d] : 0.f);
        acc += hg * Wc[d * NCLS + c];
    }
    for (int p = 0; p < PFEAT; ++p) acc += perm[b * PFEAT + p] * Wc[(DH + p) * NCLS + c];
    out[t] = acc;
}

extern "C" void kernel_launch(void* const* d_in, const int* in_sizes, int n_in,
                              void* d_out, int out_size, void* d_ws, size_t ws_size,
                              hipStream_t stream) {
    const float* h    = (const float*)d_in[0];
    const int*   src  = (const int*)d_in[1];
    const int*   dst  = (const int*)d_in[2];
    const int*   gid  = (const int*)d_in[3];
    const float* perm = (const float*)d_in[4];
    const float* W1   = (const float*)d_in[5];
    const float* b1   = (const float*)d_in[6];
    const float* W2   = (const float*)d_in[7];
    const float* b2   = (const float*)d_in[8];
    const float* Wc   = (const float*)d_in[9];
    const float* bc   = (const float*)d_in[10];
    float* out = (float*)d_out;

    char* ws = (char*)d_ws;
    size_t off = 0;
    auto alloc = [&](size_t bytes) {
        void* p = ws + off;
        off = (off + bytes + 255) & ~(size_t)255;
        return p;
    };
    int*   deg     = (int*)alloc(N_NODES * 4);
    int*   row_ptr = (int*)alloc((N_NODES + 1) * 4);
    int*   col     = (int*)alloc(N_EDGES * 4);
    int*   epos    = (int*)alloc(N_EDGES * 4);
    int*   bsum    = (int*)alloc(SCAN_BLOCKS * 4);
    float* norm    = (float*)alloc(N_NODES * 4);
    unsigned short* h_bf = (unsigned short*)alloc((size_t)NPAD * 128 * 2);
    unsigned short* f1   = (unsigned short*)alloc((size_t)NPAD * 128 * 2);
    unsigned short* f2   = (unsigned short*)alloc((size_t)NPAD * 128 * 2);
    unsigned short* x2   = (unsigned short*)alloc((size_t)NPAD * 128 * 2);
    unsigned short* Wt1  = (unsigned short*)alloc(384 * 128 * 2);
    unsigned short* Wt2  = (unsigned short*)alloc(384 * 128 * 2);
    float* gsum    = (float*)alloc(B_GRAPHS * 128 * 4);
    int*   gstart  = (int*)alloc(B_GRAPHS * 4);

    // one fused init dispatch: zeroing + h->bf16 + W transposes
    k_init<<<(NCVT4 + 255) / 256, 256, 0, stream>>>(h, h_bf, W1, W2, Wt1, Wt2,
                                                    deg, gsum, gstart);
    // CSR build: deg+positions -> norm+bsum -> scan -> scatter (atomic-free)
    k_deg_bound<<<(N_EDGES + N_NODES + 255) / 256, 256, 0, stream>>>(dst, gid, deg, epos, gstart);
    k_norm_bsum<<<SCAN_BLOCKS, 256, 0, stream>>>(deg, norm, bsum);
    k_scan2<<<SCAN_BLOCKS, 256, 0, stream>>>(deg, bsum, row_ptr);
    k_scatter<<<(N_EDGES + 255) / 256, 256, 0, stream>>>(src, dst, row_ptr, epos, col);

    int spmm_grid = (N_NODES + 3) / 4;
    int gemm_grid = (N_NODES + 127) / 128;

    // Layer 1: feats = [h, f1, f2] -> x2 (relu, bf16)
    k_spmm<<<spmm_grid, 256, 0, stream>>>(h_bf, norm, row_ptr, col, f1);
    k_spmm<<<spmm_grid, 256, 0, stream>>>(f1, norm, row_ptr, col, f2);
    k_gemm_mfma<true, false><<<gemm_grid, 256, 0, stream>>>(h_bf, f1, f2, Wt1, b1, x2, gid, gsum);

    // Layer 2: feats = [x2, f1, f2] -> fused mean-pool numerator
    k_spmm<<<spmm_grid, 256, 0, stream>>>(x2, norm, row_ptr, col, f1);
    k_spmm<<<spmm_grid, 256, 0, stream>>>(f1, norm, row_ptr, col, f2);
    k_gemm_mfma<false, true><<<gemm_grid, 256, 0, stream>>>(x2, f1, f2, Wt2, nullptr, nullptr, gid, gsum);

    // Readout
    k_final<<<1, 128, 0, stream>>>(gsum, gstart, b2, perm, Wc, bc, out);
}